// Round 11
// baseline (292.031 us; speedup 1.0000x reference)
//
#include <hip/hip_runtime.h>

#define N_NODES 100000
#define N_EDGES 1600000
#define IN_DIM 256
#define OUT_DIM 128
#define SCAN_B 1024
#define SCAN_NB 98   // ceil(100000/1024)
#define BROWS 100    // rows per bucket
#define NBK 1000     // buckets
#define PBLK 128     // partition blocks
#define EPB 12500    // edges per partition block

typedef __attribute__((ext_vector_type(4))) float f32x4;
typedef __attribute__((ext_vector_type(8))) short s16x8;

__device__ inline unsigned short f2bf(float f) {
    union { float f; unsigned int u; } a; a.f = f;
    unsigned int r = a.u + 0x7fffu + ((a.u >> 16) & 1u);
    return (unsigned short)(r >> 16);
}
__device__ inline float bf2f(unsigned short h) {
    union { unsigned int u; float f; } a; a.u = ((unsigned int)h) << 16;
    return a.f;
}

// ---------------- Kernel 0: u = fsW @ wi, v = fsW @ wj ----------------
__global__ void kuv(const float* __restrict__ fsW, const float* __restrict__ fw,
                    float* __restrict__ u, float* __restrict__ v) {
    __shared__ float wi[128], wj[128];
    int t = threadIdx.x;
    if (t < 128) wi[t] = fw[t]; else wj[t - 128] = fw[t];
    __syncthreads();
    const float* rowp = fsW + (size_t)t * OUT_DIM;
    float su = 0.f, sv = 0.f;
    for (int d = 0; d < 128; d += 4) {
        float4 a = *(const float4*)(rowp + d);
        su += a.x * wi[d] + a.y * wi[d + 1] + a.z * wi[d + 2] + a.w * wi[d + 3];
        sv += a.x * wj[d] + a.y * wj[d + 1] + a.z * wj[d + 2] + a.w * wj[d + 3];
    }
    u[t] = su; v[t] = sv;
}

// ---------------- Kernel 0b: wt[n][k] = bf16(W[k][n]) ----------------
__global__ void kwt(const float* __restrict__ W, unsigned short* __restrict__ wt) {
    int n = blockIdx.x;
    int k = threadIdx.x;
    wt[n * 256 + k] = f2bf(W[(size_t)k * 128 + n]);
}

// ------- Kernel 1: LDS-free MFMA GEMM. One wave = 16 rows x 128 cols. -------
// A-frags straight from global x (f32->bf16 in-register, each element read once);
// B-frags from wt (64 KB, L1/L2-hot). si/sj fused on the same A registers.
__global__ __launch_bounds__(256) void gemm_mfma(
        const float* __restrict__ x, const unsigned short* __restrict__ wt,
        const float* __restrict__ u, const float* __restrict__ v,
        unsigned short* __restrict__ psb, float* __restrict__ si, float* __restrict__ sj) {
    const int t = threadIdx.x;
    const int wave = t >> 6, lane = t & 63;
    const int l15 = lane & 15, lhi = lane >> 4;
    const int rb = blockIdx.x * 64 + wave * 16;    // wave-uniform; 100000 % 16 == 0
    if (rb >= N_NODES) return;                      // whole-wave exit, no barriers used

    const int arow = rb + l15;
    const float* xp = x + (size_t)arow * IN_DIM + lhi * 8;
    const float* up = u + lhi * 8;
    const float* vp = v + lhi * 8;
    const unsigned short* wp = wt + (size_t)l15 * IN_DIM + lhi * 8;

    f32x4 acc[8];
#pragma unroll
    for (int ni = 0; ni < 8; ++ni) acc[ni] = (f32x4){0.f, 0.f, 0.f, 0.f};
    float su = 0.f, sv = 0.f;

#pragma unroll 2
    for (int ks = 0; ks < 8; ++ks) {
        const int ko = ks * 32;
        float4 a0 = *(const float4*)(xp + ko);
        float4 a1 = *(const float4*)(xp + ko + 4);
        float4 u0 = *(const float4*)(up + ko);
        float4 u1 = *(const float4*)(up + ko + 4);
        float4 v0 = *(const float4*)(vp + ko);
        float4 v1 = *(const float4*)(vp + ko + 4);
        su = fmaf(a0.x, u0.x, su); su = fmaf(a0.y, u0.y, su);
        su = fmaf(a0.z, u0.z, su); su = fmaf(a0.w, u0.w, su);
        su = fmaf(a1.x, u1.x, su); su = fmaf(a1.y, u1.y, su);
        su = fmaf(a1.z, u1.z, su); su = fmaf(a1.w, u1.w, su);
        sv = fmaf(a0.x, v0.x, sv); sv = fmaf(a0.y, v0.y, sv);
        sv = fmaf(a0.z, v0.z, sv); sv = fmaf(a0.w, v0.w, sv);
        sv = fmaf(a1.x, v1.x, sv); sv = fmaf(a1.y, v1.y, sv);
        sv = fmaf(a1.z, v1.z, sv); sv = fmaf(a1.w, v1.w, sv);
        union { unsigned short h[8]; s16x8 s; } af;
        af.h[0] = f2bf(a0.x); af.h[1] = f2bf(a0.y); af.h[2] = f2bf(a0.z); af.h[3] = f2bf(a0.w);
        af.h[4] = f2bf(a1.x); af.h[5] = f2bf(a1.y); af.h[6] = f2bf(a1.z); af.h[7] = f2bf(a1.w);
#pragma unroll
        for (int ni = 0; ni < 8; ++ni) {
            s16x8 bf = *(const s16x8*)(wp + (size_t)ni * 16 * IN_DIM + ko);
            acc[ni] = __builtin_amdgcn_mfma_f32_16x16x32_bf16(af.s, bf, acc[ni], 0, 0, 0);
        }
    }

    // si/sj: reduce lhi groups (lanes l15, l15+16, l15+32, l15+48)
    su += __shfl_xor(su, 16); su += __shfl_xor(su, 32);
    sv += __shfl_xor(sv, 16); sv += __shfl_xor(sv, 32);
    if (lhi == 0) { si[arow] = su; sj[arow] = sv; }

    // C write: D frag mapping col=lane&15, row=(lane>>4)*4+j
#pragma unroll
    for (int ni = 0; ni < 8; ++ni) {
        const int colb = ni * 16 + l15;
#pragma unroll
        for (int j = 0; j < 4; ++j) {
            psb[(size_t)(rb + lhi * 4 + j) * OUT_DIM + colb] = f2bf(acc[ni][j]);
        }
    }
}

// ---------------- Kernel 2: node degree histogram ----------------
__global__ void khist(const int* __restrict__ row, int* __restrict__ deg) {
    int e = blockIdx.x * 256 + threadIdx.x;
    if (e < N_EDGES) atomicAdd(&deg[row[e]], 1);
}

// ---------------- Kernel 3a/b/c: node-level exclusive scan -> offs ----------------
__global__ void kscan1(const int* __restrict__ deg, int* __restrict__ offs,
                       int* __restrict__ bsum) {
    int i = blockIdx.x * SCAN_B + threadIdx.x;
    int vv = (i < N_NODES) ? deg[i] : 0;
    int lane = threadIdx.x & 63, wid = threadIdx.x >> 6;
    int s = vv;
#pragma unroll
    for (int o = 1; o < 64; o <<= 1) { int tt = __shfl_up(s, o); if (lane >= o) s += tt; }
    __shared__ int wsum[16];
    if (lane == 63) wsum[wid] = s;
    __syncthreads();
    if (threadIdx.x < 16) {
        int tt = wsum[threadIdx.x]; int ss = tt;
#pragma unroll
        for (int o = 1; o < 16; o <<= 1) { int uu = __shfl_up(ss, o); if ((int)threadIdx.x >= o) ss += uu; }
        wsum[threadIdx.x] = ss - tt;
    }
    __syncthreads();
    int excl = s - vv + wsum[wid];
    if (i < N_NODES) offs[i] = excl;
    if (threadIdx.x == SCAN_B - 1) bsum[blockIdx.x] = s + wsum[wid];
}

__global__ void kscan2(const int* __restrict__ bsum, int* __restrict__ boff) {
    int i = threadIdx.x;
    int vv = (i < SCAN_NB) ? bsum[i] : 0;
    int lane = i & 63, wid = i >> 6;
    int s = vv;
#pragma unroll
    for (int o = 1; o < 64; o <<= 1) { int tt = __shfl_up(s, o); if (lane >= o) s += tt; }
    __shared__ int wsum2[2];
    if (lane == 63) wsum2[wid] = s;
    __syncthreads();
    int base = (wid == 1) ? wsum2[0] : 0;
    if (i < SCAN_NB) boff[i] = s - vv + base;
}

__global__ void kscan3(int* __restrict__ offs, const int* __restrict__ boff) {
    int i = blockIdx.x * SCAN_B + threadIdx.x;
    if (i < N_NODES) offs[i] += boff[blockIdx.x];
}

// ------- Kernel 4a: per-(block,bucket) histogram -------
__global__ __launch_bounds__(256) void khist1(const int* __restrict__ row,
                                              int* __restrict__ hist_t) {
    __shared__ int h[NBK];
    const int t = threadIdx.x, blk = blockIdx.x;
    for (int b = t; b < NBK; b += 256) h[b] = 0;
    __syncthreads();
    const int e0 = blk * EPB;
    for (int i = t; i < EPB; i += 256) {
        int r = row[e0 + i];
        atomicAdd(&h[r / BROWS], 1);
    }
    __syncthreads();
    for (int b = t; b < NBK; b += 256)
        hist_t[b * PBLK + blk] = h[b];
}

// ------- Kernel 4b: per-(bucket,block) offsets (bucket base = offs[b*BROWS]) -------
__global__ __launch_bounds__(128) void koff(const int* __restrict__ hist_t,
                                            const int* __restrict__ offs,
                                            int* __restrict__ off) {
    const int b = blockIdx.x, t = threadIdx.x;
    const int lane = t & 63, w = t >> 6;
    int v = hist_t[b * PBLK + t];
    int s = v;
#pragma unroll
    for (int o = 1; o < 64; o <<= 1) { int tt = __shfl_up(s, o); if (lane >= o) s += tt; }
    __shared__ int ws2[2];
    if (lane == 63) ws2[w] = s;
    __syncthreads();
    int base = (w == 1) ? ws2[0] : 0;
    off[b * PBLK + t] = offs[b * BROWS] + base + (s - v);
}

// ------- Kernel 4c: partition edges into bucket-contiguous runs (packed 4B) -------
__global__ __launch_bounds__(256) void kpart1(const int* __restrict__ row,
                                              const int* __restrict__ col,
                                              const int* __restrict__ off,
                                              unsigned int* __restrict__ part) {
    __shared__ int cur[NBK];
    const int t = threadIdx.x, blk = blockIdx.x;
    for (int b = t; b < NBK; b += 256) cur[b] = off[b * PBLK + blk];
    __syncthreads();
    const int e0 = blk * EPB;
    for (int i = t; i < EPB; i += 256) {
        int r = row[e0 + i], c = col[e0 + i];
        int b = r / BROWS;
        int rl = r - b * BROWS;
        int pos = atomicAdd(&cur[b], 1);
        part[pos] = ((unsigned)rl << 17) | (unsigned)c;
    }
}

// ------- Kernel 4d: per-bucket CSR finalize + edge value (L2-local window) -------
__global__ __launch_bounds__(256) void kpart2(const unsigned int* __restrict__ part,
                                              const int* __restrict__ offs,
                                              const float* __restrict__ si,
                                              const float* __restrict__ sj,
                                              const float* __restrict__ dia,
                                              const float* __restrict__ fb,
                                              int2* __restrict__ epack) {
    __shared__ int cur[BROWS];
    __shared__ float sil[BROWS], dial[BROWS];
    const int b = blockIdx.x, t = threadIdx.x;
    const int rbase = b * BROWS;
    if (t < BROWS) {
        cur[t] = offs[rbase + t];
        sil[t] = si[rbase + t];
        dial[t] = dia[rbase + t];
    }
    __syncthreads();
    const int bstart = offs[rbase];
    const int bend = (b == NBK - 1) ? N_EDGES : offs[rbase + BROWS];
    const float fbv = fb[0];
    for (int e = bstart + t; e < bend; e += 256) {
        unsigned pk = part[e];
        int rl = (int)(pk >> 17);
        int c = (int)(pk & 0x1FFFFu);
        float tval = sil[rl] + sj[c] + fbv;
        float sg = 1.f / (1.f + expf(-tval));
        float l2 = log2f(dial[rl] * dia[c]);
        float val = exp2f(-sg * l2);
        int pos = atomicAdd(&cur[rl], 1);
        epack[pos] = make_int2(c, __float_as_int(val));
    }
}

// ------- Kernel 5: per-node gather-accumulate + ReLU (round-4 proven) -------
__global__ __launch_bounds__(256) void kgather(
        const int* __restrict__ offs, const int* __restrict__ deg,
        const int2* __restrict__ epack,
        const unsigned short* __restrict__ psb, float* __restrict__ out) {
    int lane = threadIdx.x & 31;
    int node = blockIdx.x * 8 + (threadIdx.x >> 5);
    if (node >= N_NODES) return;
    int start = offs[node], d = deg[node];
    const int2* ep = epack + start;
    float a0 = 0.f, a1 = 0.f, a2 = 0.f, a3 = 0.f;
    int k = 0;
    for (; k + 2 <= d; k += 2) {
        int2 e0 = ep[k], e1 = ep[k + 1];
        float v0 = __int_as_float(e0.y), v1 = __int_as_float(e1.y);
        ushort4 p0 = *(const ushort4*)&psb[(size_t)e0.x * OUT_DIM + lane * 4];
        ushort4 p1 = *(const ushort4*)&psb[(size_t)e1.x * OUT_DIM + lane * 4];
        a0 = fmaf(v0, bf2f(p0.x), a0); a0 = fmaf(v1, bf2f(p1.x), a0);
        a1 = fmaf(v0, bf2f(p0.y), a1); a1 = fmaf(v1, bf2f(p1.y), a1);
        a2 = fmaf(v0, bf2f(p0.z), a2); a2 = fmaf(v1, bf2f(p1.z), a2);
        a3 = fmaf(v0, bf2f(p0.w), a3); a3 = fmaf(v1, bf2f(p1.w), a3);
    }
    if (k < d) {
        int2 e0 = ep[k];
        float v0 = __int_as_float(e0.y);
        ushort4 p0 = *(const ushort4*)&psb[(size_t)e0.x * OUT_DIM + lane * 4];
        a0 = fmaf(v0, bf2f(p0.x), a0);
        a1 = fmaf(v0, bf2f(p0.y), a1);
        a2 = fmaf(v0, bf2f(p0.z), a2);
        a3 = fmaf(v0, bf2f(p0.w), a3);
    }
    float4 o;
    o.x = fmaxf(a0, 0.f); o.y = fmaxf(a1, 0.f);
    o.z = fmaxf(a2, 0.f); o.w = fmaxf(a3, 0.f);
    *(float4*)&out[(size_t)node * OUT_DIM + lane * 4] = o;
}

extern "C" void kernel_launch(void* const* d_in, const int* in_sizes, int n_in,
                              void* d_out, int out_size, void* d_ws, size_t ws_size,
                              hipStream_t stream) {
    const float* x   = (const float*)d_in[0];
    const float* W   = (const float*)d_in[1];
    const float* fsW = (const float*)d_in[2];
    const float* fw  = (const float*)d_in[3];
    const float* fb  = (const float*)d_in[4];
    const float* dia = (const float*)d_in[5];
    const int*   row = (const int*)d_in[6];
    const int*   col = (const int*)d_in[7];
    float* out = (float*)d_out;

    char* p = (char*)d_ws;
    auto alloc = [&](size_t bytes) -> char* {
        char* r = p; p += (bytes + 255) & ~(size_t)255; return r;
    };
    float* u      = (float*)alloc(256 * 4);
    float* v      = (float*)alloc(256 * 4);
    unsigned short* wtb = (unsigned short*)alloc((size_t)128 * 256 * 2);
    float* si     = (float*)alloc((size_t)N_NODES * 4);
    float* sj     = (float*)alloc((size_t)N_NODES * 4);
    int*   deg    = (int*)alloc((size_t)N_NODES * 4);
    int*   offs   = (int*)alloc((size_t)N_NODES * 4);
    int*   bsum   = (int*)alloc(128 * 4);
    int*   boff   = (int*)alloc(128 * 4);
    unsigned short* psb = (unsigned short*)alloc((size_t)N_NODES * OUT_DIM * 2);
    int*   hist_t = (int*)alloc((size_t)NBK * PBLK * 4);
    int*   off    = (int*)alloc((size_t)NBK * PBLK * 4);
    unsigned int* part = (unsigned int*)alloc((size_t)N_EDGES * 4);
    int2*  epack  = (int2*)alloc((size_t)N_EDGES * 8);

    (void)hipMemsetAsync(deg, 0, (size_t)N_NODES * 4, stream);

    kuv<<<1, 256, 0, stream>>>(fsW, fw, u, v);
    kwt<<<128, 256, 0, stream>>>(W, wtb);
    gemm_mfma<<<(N_NODES + 63) / 64, 256, 0, stream>>>(x, wtb, u, v, psb, si, sj);
    khist<<<N_EDGES / 256, 256, 0, stream>>>(row, deg);
    kscan1<<<SCAN_NB, SCAN_B, 0, stream>>>(deg, offs, bsum);
    kscan2<<<1, 128, 0, stream>>>(bsum, boff);
    kscan3<<<SCAN_NB, SCAN_B, 0, stream>>>(offs, boff);
    khist1<<<PBLK, 256, 0, stream>>>(row, hist_t);
    koff<<<NBK, PBLK, 0, stream>>>(hist_t, offs, off);
    kpart1<<<PBLK, 256, 0, stream>>>(row, col, off, part);
    kpart2<<<NBK, 256, 0, stream>>>(part, offs, si, sj, dia, fb, epack);
    kgather<<<N_NODES / 8, 256, 0, stream>>>(offs, deg, epack, psb, out);
}

// Round 12
// 274.084 us; speedup vs baseline: 1.0655x; 1.0655x over previous
//
#include <hip/hip_runtime.h>

#define N_NODES 100000
#define N_EDGES 1600000
#define IN_DIM 256
#define OUT_DIM 128
#define SCAN_B 1024
#define SCAN_NB 98   // ceil(100000/1024)
#define BROWS 100    // rows per bucket
#define NBK 1000     // buckets
#define PBLK 128     // partition blocks
#define EPB 12500    // edges per partition block

typedef __attribute__((ext_vector_type(4))) float f32x4;
typedef __attribute__((ext_vector_type(8))) short s16x8;

__device__ inline unsigned short f2bf(float f) {
    union { float f; unsigned int u; } a; a.f = f;
    unsigned int r = a.u + 0x7fffu + ((a.u >> 16) & 1u);
    return (unsigned short)(r >> 16);
}
__device__ inline float bf2f(unsigned short h) {
    union { unsigned int u; float f; } a; a.u = ((unsigned int)h) << 16;
    return a.f;
}

// ---------------- Kernel 0: u = fsW @ wi, v = fsW @ wj ----------------
__global__ void kuv(const float* __restrict__ fsW, const float* __restrict__ fw,
                    float* __restrict__ u, float* __restrict__ v) {
    __shared__ float wi[128], wj[128];
    int t = threadIdx.x;
    if (t < 128) wi[t] = fw[t]; else wj[t - 128] = fw[t];
    __syncthreads();
    const float* rowp = fsW + (size_t)t * OUT_DIM;
    float su = 0.f, sv = 0.f;
    for (int d = 0; d < 128; d += 4) {
        float4 a = *(const float4*)(rowp + d);
        su += a.x * wi[d] + a.y * wi[d + 1] + a.z * wi[d + 2] + a.w * wi[d + 3];
        sv += a.x * wj[d] + a.y * wj[d + 1] + a.z * wj[d + 2] + a.w * wj[d + 3];
    }
    u[t] = su; v[t] = sv;
}

// ---------------- Kernel 0b: wt[n][k] = bf16(W[k][n]) ----------------
__global__ void kwt(const float* __restrict__ W, unsigned short* __restrict__ wt) {
    int n = blockIdx.x;
    int k = threadIdx.x;
    wt[n * 256 + k] = f2bf(W[(size_t)k * 128 + n]);
}

// ------- Kernel 1: hybrid MFMA GEMM: x staged in LDS (17.4 KB), B direct from wt -------
// Block: 256 thr (4 waves). Tile: 64 nodes x 128 cols, K in 2 phases of 128.
// Wave w computes cols [w*32, w*32+32). si/sj fused into the f32 staging pass.
__global__ __launch_bounds__(256) void gemm_mfma(
        const float* __restrict__ x, const unsigned short* __restrict__ wt,
        const float* __restrict__ u, const float* __restrict__ v,
        unsigned short* __restrict__ psb, float* __restrict__ si, float* __restrict__ sj) {
    __shared__ unsigned short xa[64 * 136];    // 17408 B only

    const int t = threadIdx.x;
    const int wave = t >> 6, lane = t & 63;
    const int l15 = lane & 15, lhi = lane >> 4;
    const int row = t >> 2, quad = t & 3;      // staging roles
    const int brow = blockIdx.x * 64;
    const int gnode = brow + row;
    const bool valid = gnode < N_NODES;

    f32x4 acc[4][2];
#pragma unroll
    for (int mi = 0; mi < 4; ++mi)
#pragma unroll
        for (int ni = 0; ni < 2; ++ni) acc[mi][ni] = (f32x4){0.f, 0.f, 0.f, 0.f};
    float su = 0.f, sv = 0.f;

#pragma unroll
    for (int ph = 0; ph < 2; ++ph) {
        // ---- stage x half-tile (64 nodes x 128 k), f32 -> bf16, + si/sj partials ----
        {
            const float* xp = x + (size_t)gnode * IN_DIM + ph * 128 + quad * 32;
            const float* up = u + ph * 128 + quad * 32;
            const float* vp = v + ph * 128 + quad * 32;
#pragma unroll
            for (int cc = 0; cc < 4; ++cc) {
                float4 a0 = make_float4(0.f, 0.f, 0.f, 0.f), a1 = a0;
                if (valid) {
                    a0 = ((const float4*)xp)[cc * 2];
                    a1 = ((const float4*)xp)[cc * 2 + 1];
                    float4 u0 = ((const float4*)up)[cc * 2], u1 = ((const float4*)up)[cc * 2 + 1];
                    float4 v0 = ((const float4*)vp)[cc * 2], v1 = ((const float4*)vp)[cc * 2 + 1];
                    su = fmaf(a0.x, u0.x, su); su = fmaf(a0.y, u0.y, su);
                    su = fmaf(a0.z, u0.z, su); su = fmaf(a0.w, u0.w, su);
                    su = fmaf(a1.x, u1.x, su); su = fmaf(a1.y, u1.y, su);
                    su = fmaf(a1.z, u1.z, su); su = fmaf(a1.w, u1.w, su);
                    sv = fmaf(a0.x, v0.x, sv); sv = fmaf(a0.y, v0.y, sv);
                    sv = fmaf(a0.z, v0.z, sv); sv = fmaf(a0.w, v0.w, sv);
                    sv = fmaf(a1.x, v1.x, sv); sv = fmaf(a1.y, v1.y, sv);
                    sv = fmaf(a1.z, v1.z, sv); sv = fmaf(a1.w, v1.w, sv);
                }
                union { unsigned short h[8]; uint4 q; } pk;
                pk.h[0] = f2bf(a0.x); pk.h[1] = f2bf(a0.y); pk.h[2] = f2bf(a0.z); pk.h[3] = f2bf(a0.w);
                pk.h[4] = f2bf(a1.x); pk.h[5] = f2bf(a1.y); pk.h[6] = f2bf(a1.z); pk.h[7] = f2bf(a1.w);
                *(uint4*)&xa[row * 136 + quad * 32 + cc * 8] = pk.q;
            }
        }
        __syncthreads();

        // ---- 4 K-steps of MFMA; B-fragments straight from global wt (L2-hot) ----
#pragma unroll
        for (int ks = 0; ks < 4; ++ks) {
            const int k0 = ks * 32 + lhi * 8;
            s16x8 afr[4], bfr[2];
#pragma unroll
            for (int mi = 0; mi < 4; ++mi)
                afr[mi] = *(const s16x8*)&xa[(mi * 16 + l15) * 136 + k0];
#pragma unroll
            for (int ni = 0; ni < 2; ++ni)
                bfr[ni] = *(const s16x8*)(wt + (size_t)(wave * 32 + ni * 16 + l15) * IN_DIM
                                          + ph * 128 + k0);
#pragma unroll
            for (int mi = 0; mi < 4; ++mi)
#pragma unroll
                for (int ni = 0; ni < 2; ++ni)
                    acc[mi][ni] = __builtin_amdgcn_mfma_f32_16x16x32_bf16(
                        afr[mi], bfr[ni], acc[mi][ni], 0, 0, 0);
        }
        __syncthreads();
    }

    su += __shfl_xor(su, 1); su += __shfl_xor(su, 2);
    sv += __shfl_xor(sv, 1); sv += __shfl_xor(sv, 2);
    if (quad == 0 && valid) { si[gnode] = su; sj[gnode] = sv; }

    // C write: D frag mapping col=lane&15, row=(lane>>4)*4+j
#pragma unroll
    for (int mi = 0; mi < 4; ++mi) {
        int node = brow + mi * 16 + lhi * 4;
#pragma unroll
        for (int ni = 0; ni < 2; ++ni) {
            int colb = wave * 32 + ni * 16 + l15;
#pragma unroll
            for (int j = 0; j < 4; ++j) {
                if (node + j < N_NODES)
                    psb[(size_t)(node + j) * OUT_DIM + colb] = f2bf(acc[mi][ni][j]);
            }
        }
    }
}

// ---------------- Kernel 2: node degree histogram ----------------
__global__ void khist(const int* __restrict__ row, int* __restrict__ deg) {
    int e = blockIdx.x * 256 + threadIdx.x;
    if (e < N_EDGES) atomicAdd(&deg[row[e]], 1);
}

// ---------------- Kernel 3a/b/c: node-level exclusive scan -> offs ----------------
__global__ void kscan1(const int* __restrict__ deg, int* __restrict__ offs,
                       int* __restrict__ bsum) {
    int i = blockIdx.x * SCAN_B + threadIdx.x;
    int vv = (i < N_NODES) ? deg[i] : 0;
    int lane = threadIdx.x & 63, wid = threadIdx.x >> 6;
    int s = vv;
#pragma unroll
    for (int o = 1; o < 64; o <<= 1) { int tt = __shfl_up(s, o); if (lane >= o) s += tt; }
    __shared__ int wsum[16];
    if (lane == 63) wsum[wid] = s;
    __syncthreads();
    if (threadIdx.x < 16) {
        int tt = wsum[threadIdx.x]; int ss = tt;
#pragma unroll
        for (int o = 1; o < 16; o <<= 1) { int uu = __shfl_up(ss, o); if ((int)threadIdx.x >= o) ss += uu; }
        wsum[threadIdx.x] = ss - tt;
    }
    __syncthreads();
    int excl = s - vv + wsum[wid];
    if (i < N_NODES) offs[i] = excl;
    if (threadIdx.x == SCAN_B - 1) bsum[blockIdx.x] = s + wsum[wid];
}

__global__ void kscan2(const int* __restrict__ bsum, int* __restrict__ boff) {
    int i = threadIdx.x;
    int vv = (i < SCAN_NB) ? bsum[i] : 0;
    int lane = i & 63, wid = i >> 6;
    int s = vv;
#pragma unroll
    for (int o = 1; o < 64; o <<= 1) { int tt = __shfl_up(s, o); if (lane >= o) s += tt; }
    __shared__ int wsum2[2];
    if (lane == 63) wsum2[wid] = s;
    __syncthreads();
    int base = (wid == 1) ? wsum2[0] : 0;
    if (i < SCAN_NB) boff[i] = s - vv + base;
}

__global__ void kscan3(int* __restrict__ offs, const int* __restrict__ boff) {
    int i = blockIdx.x * SCAN_B + threadIdx.x;
    if (i < N_NODES) offs[i] += boff[blockIdx.x];
}

// ------- Kernel 4a: per-(block,bucket) histogram -------
__global__ __launch_bounds__(256) void khist1(const int* __restrict__ row,
                                              int* __restrict__ hist_t) {
    __shared__ int h[NBK];
    const int t = threadIdx.x, blk = blockIdx.x;
    for (int b = t; b < NBK; b += 256) h[b] = 0;
    __syncthreads();
    const int e0 = blk * EPB;
    for (int i = t; i < EPB; i += 256) {
        int r = row[e0 + i];
        atomicAdd(&h[r / BROWS], 1);
    }
    __syncthreads();
    for (int b = t; b < NBK; b += 256)
        hist_t[b * PBLK + blk] = h[b];
}

// ------- Kernel 4b: per-(bucket,block) offsets (bucket base = offs[b*BROWS]) -------
__global__ __launch_bounds__(128) void koff(const int* __restrict__ hist_t,
                                            const int* __restrict__ offs,
                                            int* __restrict__ off) {
    const int b = blockIdx.x, t = threadIdx.x;
    const int lane = t & 63, w = t >> 6;
    int v = hist_t[b * PBLK + t];
    int s = v;
#pragma unroll
    for (int o = 1; o < 64; o <<= 1) { int tt = __shfl_up(s, o); if (lane >= o) s += tt; }
    __shared__ int ws2[2];
    if (lane == 63) ws2[w] = s;
    __syncthreads();
    int base = (w == 1) ? ws2[0] : 0;
    off[b * PBLK + t] = offs[b * BROWS] + base + (s - v);
}

// ------- Kernel 4c: partition edges into bucket-contiguous runs (packed 4B) -------
__global__ __launch_bounds__(256) void kpart1(const int* __restrict__ row,
                                              const int* __restrict__ col,
                                              const int* __restrict__ off,
                                              unsigned int* __restrict__ part) {
    __shared__ int cur[NBK];
    const int t = threadIdx.x, blk = blockIdx.x;
    for (int b = t; b < NBK; b += 256) cur[b] = off[b * PBLK + blk];
    __syncthreads();
    const int e0 = blk * EPB;
    for (int i = t; i < EPB; i += 256) {
        int r = row[e0 + i], c = col[e0 + i];
        int b = r / BROWS;
        int rl = r - b * BROWS;
        int pos = atomicAdd(&cur[b], 1);
        part[pos] = ((unsigned)rl << 17) | (unsigned)c;
    }
}

// ------- Kernel 4d: per-bucket CSR finalize + edge value (L2-local window) -------
__global__ __launch_bounds__(256) void kpart2(const unsigned int* __restrict__ part,
                                              const int* __restrict__ offs,
                                              const float* __restrict__ si,
                                              const float* __restrict__ sj,
                                              const float* __restrict__ dia,
                                              const float* __restrict__ fb,
                                              int2* __restrict__ epack) {
    __shared__ int cur[BROWS];
    __shared__ float sil[BROWS], dial[BROWS];
    const int b = blockIdx.x, t = threadIdx.x;
    const int rbase = b * BROWS;
    if (t < BROWS) {
        cur[t] = offs[rbase + t];
        sil[t] = si[rbase + t];
        dial[t] = dia[rbase + t];
    }
    __syncthreads();
    const int bstart = offs[rbase];
    const int bend = (b == NBK - 1) ? N_EDGES : offs[rbase + BROWS];
    const float fbv = fb[0];
    for (int e = bstart + t; e < bend; e += 256) {
        unsigned pk = part[e];
        int rl = (int)(pk >> 17);
        int c = (int)(pk & 0x1FFFFu);
        float tval = sil[rl] + sj[c] + fbv;
        float sg = 1.f / (1.f + expf(-tval));
        float l2 = log2f(dial[rl] * dia[c]);
        float val = exp2f(-sg * l2);
        int pos = atomicAdd(&cur[rl], 1);
        epack[pos] = make_int2(c, __float_as_int(val));
    }
}

// ------- Kernel 5: per-node gather-accumulate + ReLU (round-4 proven) -------
__global__ __launch_bounds__(256) void kgather(
        const int* __restrict__ offs, const int* __restrict__ deg,
        const int2* __restrict__ epack,
        const unsigned short* __restrict__ psb, float* __restrict__ out) {
    int lane = threadIdx.x & 31;
    int node = blockIdx.x * 8 + (threadIdx.x >> 5);
    if (node >= N_NODES) return;
    int start = offs[node], d = deg[node];
    const int2* ep = epack + start;
    float a0 = 0.f, a1 = 0.f, a2 = 0.f, a3 = 0.f;
    int k = 0;
    for (; k + 2 <= d; k += 2) {
        int2 e0 = ep[k], e1 = ep[k + 1];
        float v0 = __int_as_float(e0.y), v1 = __int_as_float(e1.y);
        ushort4 p0 = *(const ushort4*)&psb[(size_t)e0.x * OUT_DIM + lane * 4];
        ushort4 p1 = *(const ushort4*)&psb[(size_t)e1.x * OUT_DIM + lane * 4];
        a0 = fmaf(v0, bf2f(p0.x), a0); a0 = fmaf(v1, bf2f(p1.x), a0);
        a1 = fmaf(v0, bf2f(p0.y), a1); a1 = fmaf(v1, bf2f(p1.y), a1);
        a2 = fmaf(v0, bf2f(p0.z), a2); a2 = fmaf(v1, bf2f(p1.z), a2);
        a3 = fmaf(v0, bf2f(p0.w), a3); a3 = fmaf(v1, bf2f(p1.w), a3);
    }
    if (k < d) {
        int2 e0 = ep[k];
        float v0 = __int_as_float(e0.y);
        ushort4 p0 = *(const ushort4*)&psb[(size_t)e0.x * OUT_DIM + lane * 4];
        a0 = fmaf(v0, bf2f(p0.x), a0);
        a1 = fmaf(v0, bf2f(p0.y), a1);
        a2 = fmaf(v0, bf2f(p0.z), a2);
        a3 = fmaf(v0, bf2f(p0.w), a3);
    }
    float4 o;
    o.x = fmaxf(a0, 0.f); o.y = fmaxf(a1, 0.f);
    o.z = fmaxf(a2, 0.f); o.w = fmaxf(a3, 0.f);
    *(float4*)&out[(size_t)node * OUT_DIM + lane * 4] = o;
}

extern "C" void kernel_launch(void* const* d_in, const int* in_sizes, int n_in,
                              void* d_out, int out_size, void* d_ws, size_t ws_size,
                              hipStream_t stream) {
    const float* x   = (const float*)d_in[0];
    const float* W   = (const float*)d_in[1];
    const float* fsW = (const float*)d_in[2];
    const float* fw  = (const float*)d_in[3];
    const float* fb  = (const float*)d_in[4];
    const float* dia = (const float*)d_in[5];
    const int*   row = (const int*)d_in[6];
    const int*   col = (const int*)d_in[7];
    float* out = (float*)d_out;

    char* p = (char*)d_ws;
    auto alloc = [&](size_t bytes) -> char* {
        char* r = p; p += (bytes + 255) & ~(size_t)255; return r;
    };
    float* u      = (float*)alloc(256 * 4);
    float* v      = (float*)alloc(256 * 4);
    unsigned short* wtb = (unsigned short*)alloc((size_t)128 * 256 * 2);
    float* si     = (float*)alloc((size_t)N_NODES * 4);
    float* sj     = (float*)alloc((size_t)N_NODES * 4);
    int*   deg    = (int*)alloc((size_t)N_NODES * 4);
    int*   offs   = (int*)alloc((size_t)N_NODES * 4);
    int*   bsum   = (int*)alloc(128 * 4);
    int*   boff   = (int*)alloc(128 * 4);
    unsigned short* psb = (unsigned short*)alloc((size_t)N_NODES * OUT_DIM * 2);
    int*   hist_t = (int*)alloc((size_t)NBK * PBLK * 4);
    int*   off    = (int*)alloc((size_t)NBK * PBLK * 4);
    unsigned int* part = (unsigned int*)alloc((size_t)N_EDGES * 4);
    int2*  epack  = (int2*)alloc((size_t)N_EDGES * 8);

    (void)hipMemsetAsync(deg, 0, (size_t)N_NODES * 4, stream);

    kuv<<<1, 256, 0, stream>>>(fsW, fw, u, v);
    kwt<<<128, 256, 0, stream>>>(W, wtb);
    gemm_mfma<<<(N_NODES + 63) / 64, 256, 0, stream>>>(x, wtb, u, v, psb, si, sj);
    khist<<<N_EDGES / 256, 256, 0, stream>>>(row, deg);
    kscan1<<<SCAN_NB, SCAN_B, 0, stream>>>(deg, offs, bsum);
    kscan2<<<1, 128, 0, stream>>>(bsum, boff);
    kscan3<<<SCAN_NB, SCAN_B, 0, stream>>>(offs, boff);
    khist1<<<PBLK, 256, 0, stream>>>(row, hist_t);
    koff<<<NBK, PBLK, 0, stream>>>(hist_t, offs, off);
    kpart1<<<PBLK, 256, 0, stream>>>(row, col, off, part);
    kpart2<<<NBK, 256, 0, stream>>>(part, offs, si, sj, dia, fb, epack);
    kgather<<<N_NODES / 8, 256, 0, stream>>>(offs, deg, epack, psb, out);
}

// Round 13
// 223.189 us; speedup vs baseline: 1.3084x; 1.2280x over previous
//
#include <hip/hip_runtime.h>

#define N_NODES 100000
#define N_EDGES 1600000
#define IN_DIM 256
#define OUT_DIM 128
#define BROWS 100    // rows per bucket
#define NBK 1000     // buckets (100000/100)
#define PBLK 128     // partition blocks
#define EPB 12500    // edges per partition block

typedef __attribute__((ext_vector_type(4))) float f32x4;
typedef __attribute__((ext_vector_type(8))) short s16x8;

__device__ inline unsigned short f2bf(float f) {
    union { float f; unsigned int u; } a; a.f = f;
    unsigned int r = a.u + 0x7fffu + ((a.u >> 16) & 1u);
    return (unsigned short)(r >> 16);
}
__device__ inline float bf2f(unsigned short h) {
    union { unsigned int u; float f; } a; a.u = ((unsigned int)h) << 16;
    return a.f;
}

// ---------------- Kernel 0: u = fsW @ wi, v = fsW @ wj ----------------
__global__ void kuv(const float* __restrict__ fsW, const float* __restrict__ fw,
                    float* __restrict__ u, float* __restrict__ v) {
    __shared__ float wi[128], wj[128];
    int t = threadIdx.x;
    if (t < 128) wi[t] = fw[t]; else wj[t - 128] = fw[t];
    __syncthreads();
    const float* rowp = fsW + (size_t)t * OUT_DIM;
    float su = 0.f, sv = 0.f;
    for (int d = 0; d < 128; d += 4) {
        float4 a = *(const float4*)(rowp + d);
        su += a.x * wi[d] + a.y * wi[d + 1] + a.z * wi[d + 2] + a.w * wi[d + 3];
        sv += a.x * wj[d] + a.y * wj[d + 1] + a.z * wj[d + 2] + a.w * wj[d + 3];
    }
    u[t] = su; v[t] = sv;
}

// ---------------- Kernel 0b: wt[n][k] = bf16(W[k][n]) ----------------
__global__ void kwt(const float* __restrict__ W, unsigned short* __restrict__ wt) {
    int n = blockIdx.x;
    int k = threadIdx.x;
    wt[n * 256 + k] = f2bf(W[(size_t)k * 128 + n]);
}

// ------- Kernel 1: MFMA GEMM, 32-row tile, full-K staged, ONE barrier -------
// 3125 blocks x 256 thr (exact: 3125*32 = 100000). Wave w owns cols [w*32,w*32+32).
// x staged f32->bf16 (16.9 KB), B-frags direct from L2-hot wt. si/sj fused.
__global__ __launch_bounds__(256) void gemm_mfma(
        const float* __restrict__ x, const unsigned short* __restrict__ wt,
        const float* __restrict__ u, const float* __restrict__ v,
        unsigned short* __restrict__ psb, float* __restrict__ si, float* __restrict__ sj) {
    __shared__ unsigned short xa[32 * 264];    // 16896 B

    const int t = threadIdx.x;
    const int wave = t >> 6, lane = t & 63;
    const int l15 = lane & 15, lhi = lane >> 4;
    const int row = t >> 3, oct = t & 7;       // 32 rows x 8 threads; 32 k each
    const int brow = blockIdx.x * 32;
    const int gnode = brow + row;

    // ---- stage x row-segment (32 k), f32 -> bf16, + si/sj partials ----
    {
        const float* xp = x + (size_t)gnode * IN_DIM + oct * 32;
        const float* up = u + oct * 32;
        const float* vp = v + oct * 32;
        float su = 0.f, sv = 0.f;
#pragma unroll
        for (int cc = 0; cc < 4; ++cc) {
            float4 a0 = ((const float4*)xp)[cc * 2];
            float4 a1 = ((const float4*)xp)[cc * 2 + 1];
            float4 u0 = ((const float4*)up)[cc * 2], u1 = ((const float4*)up)[cc * 2 + 1];
            float4 v0 = ((const float4*)vp)[cc * 2], v1 = ((const float4*)vp)[cc * 2 + 1];
            su = fmaf(a0.x, u0.x, su); su = fmaf(a0.y, u0.y, su);
            su = fmaf(a0.z, u0.z, su); su = fmaf(a0.w, u0.w, su);
            su = fmaf(a1.x, u1.x, su); su = fmaf(a1.y, u1.y, su);
            su = fmaf(a1.z, u1.z, su); su = fmaf(a1.w, u1.w, su);
            sv = fmaf(a0.x, v0.x, sv); sv = fmaf(a0.y, v0.y, sv);
            sv = fmaf(a0.z, v0.z, sv); sv = fmaf(a0.w, v0.w, sv);
            sv = fmaf(a1.x, v1.x, sv); sv = fmaf(a1.y, v1.y, sv);
            sv = fmaf(a1.z, v1.z, sv); sv = fmaf(a1.w, v1.w, sv);
            union { unsigned short h[8]; uint4 q; } pk;
            pk.h[0] = f2bf(a0.x); pk.h[1] = f2bf(a0.y); pk.h[2] = f2bf(a0.z); pk.h[3] = f2bf(a0.w);
            pk.h[4] = f2bf(a1.x); pk.h[5] = f2bf(a1.y); pk.h[6] = f2bf(a1.z); pk.h[7] = f2bf(a1.w);
            *(uint4*)&xa[row * 264 + oct * 32 + cc * 8] = pk.q;
        }
        // reduce si/sj across the 8 octs (consecutive lanes)
        su += __shfl_xor(su, 1); su += __shfl_xor(su, 2); su += __shfl_xor(su, 4);
        sv += __shfl_xor(sv, 1); sv += __shfl_xor(sv, 2); sv += __shfl_xor(sv, 4);
        if (oct == 0) { si[gnode] = su; sj[gnode] = sv; }
    }
    __syncthreads();   // the only barrier

    // ---- MFMA over full K; B-fragments straight from global wt (L2-hot) ----
    f32x4 acc[2][2];
#pragma unroll
    for (int mi = 0; mi < 2; ++mi)
#pragma unroll
        for (int ni = 0; ni < 2; ++ni) acc[mi][ni] = (f32x4){0.f, 0.f, 0.f, 0.f};

#pragma unroll
    for (int ks = 0; ks < 8; ++ks) {
        const int k0 = ks * 32 + lhi * 8;
        s16x8 afr[2], bfr[2];
#pragma unroll
        for (int mi = 0; mi < 2; ++mi)
            afr[mi] = *(const s16x8*)&xa[(mi * 16 + l15) * 264 + k0];
#pragma unroll
        for (int ni = 0; ni < 2; ++ni)
            bfr[ni] = *(const s16x8*)(wt + (size_t)(wave * 32 + ni * 16 + l15) * IN_DIM + k0);
#pragma unroll
        for (int mi = 0; mi < 2; ++mi)
#pragma unroll
            for (int ni = 0; ni < 2; ++ni)
                acc[mi][ni] = __builtin_amdgcn_mfma_f32_16x16x32_bf16(
                    afr[mi], bfr[ni], acc[mi][ni], 0, 0, 0);
    }

    // C write: D frag mapping col=lane&15, row=(lane>>4)*4+j
#pragma unroll
    for (int mi = 0; mi < 2; ++mi) {
        int node = brow + mi * 16 + lhi * 4;
#pragma unroll
        for (int ni = 0; ni < 2; ++ni) {
            int colb = wave * 32 + ni * 16 + l15;
#pragma unroll
            for (int j = 0; j < 4; ++j)
                psb[(size_t)(node + j) * OUT_DIM + colb] = f2bf(acc[mi][ni][j]);
        }
    }
}

// ------- Kernel 2: per-(block,bucket) histogram -------
__global__ __launch_bounds__(256) void khist1(const int* __restrict__ row,
                                              int* __restrict__ hist_t) {
    __shared__ int h[NBK];
    const int t = threadIdx.x, blk = blockIdx.x;
    for (int b = t; b < NBK; b += 256) h[b] = 0;
    __syncthreads();
    const int e0 = blk * EPB;
    for (int i = t; i < EPB; i += 256) {
        int r = row[e0 + i];
        atomicAdd(&h[r / BROWS], 1);
    }
    __syncthreads();
    for (int b = t; b < NBK; b += 256)
        hist_t[b * PBLK + blk] = h[b];
}

// ------- Kernel 3: bucket sums + exclusive scan (single block) -------
__global__ __launch_bounds__(1024) void kbscan(const int* __restrict__ hist_t,
                                               int* __restrict__ bpre) {
    __shared__ int s[1024];
    const int t = threadIdx.x;
    int v = 0;
    if (t < NBK) {
        const int* hp = hist_t + t * PBLK;
        for (int k = 0; k < PBLK; ++k) v += hp[k];
    }
    s[t] = v;
    __syncthreads();
    for (int off = 1; off < 1024; off <<= 1) {
        int nv = (t >= off) ? s[t - off] : 0;
        __syncthreads();
        s[t] += nv;
        __syncthreads();
    }
    if (t < NBK) bpre[t] = s[t] - v;
    if (t == 1023) bpre[NBK] = s[1023];
}

// ------- Kernel 4: per-(bucket,block) offsets -------
__global__ __launch_bounds__(128) void koff(const int* __restrict__ hist_t,
                                            const int* __restrict__ bpre,
                                            int* __restrict__ off) {
    const int b = blockIdx.x, t = threadIdx.x;
    const int lane = t & 63, w = t >> 6;
    int v = hist_t[b * PBLK + t];
    int s = v;
#pragma unroll
    for (int o = 1; o < 64; o <<= 1) { int tt = __shfl_up(s, o); if (lane >= o) s += tt; }
    __shared__ int ws2[2];
    if (lane == 63) ws2[w] = s;
    __syncthreads();
    int base = (w == 1) ? ws2[0] : 0;
    off[b * PBLK + t] = bpre[b] + base + (s - v);
}

// ------- Kernel 5: partition edges into bucket-contiguous runs (packed 4B) -------
__global__ __launch_bounds__(256) void kpart1(const int* __restrict__ row,
                                              const int* __restrict__ col,
                                              const int* __restrict__ off,
                                              unsigned int* __restrict__ part) {
    __shared__ int cur[NBK];
    const int t = threadIdx.x, blk = blockIdx.x;
    for (int b = t; b < NBK; b += 256) cur[b] = off[b * PBLK + blk];
    __syncthreads();
    const int e0 = blk * EPB;
    for (int i = t; i < EPB; i += 256) {
        int r = row[e0 + i], c = col[e0 + i];
        int b = r / BROWS;
        int rl = r - b * BROWS;
        int pos = atomicAdd(&cur[b], 1);
        part[pos] = ((unsigned)rl << 17) | (unsigned)c;
    }
}

// ------- Kernel 6: per-bucket row-histogram + local scan -> offs/deg, CSR + value -------
__global__ __launch_bounds__(256) void kpart2(const unsigned int* __restrict__ part,
                                              const int* __restrict__ bpre,
                                              const float* __restrict__ si,
                                              const float* __restrict__ sj,
                                              const float* __restrict__ dia,
                                              const float* __restrict__ fb,
                                              int2* __restrict__ epack,
                                              int* __restrict__ offs,
                                              int* __restrict__ deg) {
    __shared__ int cnt[BROWS];
    __shared__ int cur[BROWS];
    __shared__ float sil[BROWS], dial[BROWS];
    __shared__ int wtot[4];
    const int b = blockIdx.x, t = threadIdx.x;
    const int rbase = b * BROWS;
    if (t < BROWS) {
        cnt[t] = 0;
        sil[t] = si[rbase + t];
        dial[t] = dia[rbase + t];
    }
    __syncthreads();
    const int bstart = bpre[b], bend = bpre[b + 1];
    for (int e = bstart + t; e < bend; e += 256)
        atomicAdd(&cnt[part[e] >> 17], 1);
    __syncthreads();
    // block-wide exclusive scan of cnt[0..99] (all 256 threads participate)
    {
        int vv = (t < BROWS) ? cnt[t] : 0;
        int lane = t & 63, w = t >> 6;
        int s = vv;
#pragma unroll
        for (int o = 1; o < 64; o <<= 1) { int tt = __shfl_up(s, o); if (lane >= o) s += tt; }
        if (lane == 63) wtot[w] = s;
        __syncthreads();
        int base = 0;
        for (int k = 0; k < w; ++k) base += wtot[k];
        int excl = base + s - vv;
        if (t < BROWS) {
            cur[t] = bstart + excl;
            offs[rbase + t] = bstart + excl;
            deg[rbase + t] = vv;
        }
    }
    __syncthreads();
    const float fbv = fb[0];
    for (int e = bstart + t; e < bend; e += 256) {
        unsigned pk = part[e];
        int rl = (int)(pk >> 17);
        int c = (int)(pk & 0x1FFFFu);
        float tval = sil[rl] + sj[c] + fbv;
        float sg = 1.f / (1.f + expf(-tval));
        float l2 = log2f(dial[rl] * dia[c]);
        float val = exp2f(-sg * l2);
        int pos = atomicAdd(&cur[rl], 1);
        epack[pos] = make_int2(c, __float_as_int(val));
    }
}

// ------- Kernel 7: per-node gather-accumulate + ReLU (round-4 proven) -------
__global__ __launch_bounds__(256) void kgather(
        const int* __restrict__ offs, const int* __restrict__ deg,
        const int2* __restrict__ epack,
        const unsigned short* __restrict__ psb, float* __restrict__ out) {
    int lane = threadIdx.x & 31;
    int node = blockIdx.x * 8 + (threadIdx.x >> 5);
    if (node >= N_NODES) return;
    int start = offs[node], d = deg[node];
    const int2* ep = epack + start;
    float a0 = 0.f, a1 = 0.f, a2 = 0.f, a3 = 0.f;
    int k = 0;
    for (; k + 2 <= d; k += 2) {
        int2 e0 = ep[k], e1 = ep[k + 1];
        float v0 = __int_as_float(e0.y), v1 = __int_as_float(e1.y);
        ushort4 p0 = *(const ushort4*)&psb[(size_t)e0.x * OUT_DIM + lane * 4];
        ushort4 p1 = *(const ushort4*)&psb[(size_t)e1.x * OUT_DIM + lane * 4];
        a0 = fmaf(v0, bf2f(p0.x), a0); a0 = fmaf(v1, bf2f(p1.x), a0);
        a1 = fmaf(v0, bf2f(p0.y), a1); a1 = fmaf(v1, bf2f(p1.y), a1);
        a2 = fmaf(v0, bf2f(p0.z), a2); a2 = fmaf(v1, bf2f(p1.z), a2);
        a3 = fmaf(v0, bf2f(p0.w), a3); a3 = fmaf(v1, bf2f(p1.w), a3);
    }
    if (k < d) {
        int2 e0 = ep[k];
        float v0 = __int_as_float(e0.y);
        ushort4 p0 = *(const ushort4*)&psb[(size_t)e0.x * OUT_DIM + lane * 4];
        a0 = fmaf(v0, bf2f(p0.x), a0);
        a1 = fmaf(v0, bf2f(p0.y), a1);
        a2 = fmaf(v0, bf2f(p0.z), a2);
        a3 = fmaf(v0, bf2f(p0.w), a3);
    }
    float4 o;
    o.x = fmaxf(a0, 0.f); o.y = fmaxf(a1, 0.f);
    o.z = fmaxf(a2, 0.f); o.w = fmaxf(a3, 0.f);
    *(float4*)&out[(size_t)node * OUT_DIM + lane * 4] = o;
}

extern "C" void kernel_launch(void* const* d_in, const int* in_sizes, int n_in,
                              void* d_out, int out_size, void* d_ws, size_t ws_size,
                              hipStream_t stream) {
    const float* x   = (const float*)d_in[0];
    const float* W   = (const float*)d_in[1];
    const float* fsW = (const float*)d_in[2];
    const float* fw  = (const float*)d_in[3];
    const float* fb  = (const float*)d_in[4];
    const float* dia = (const float*)d_in[5];
    const int*   row = (const int*)d_in[6];
    const int*   col = (const int*)d_in[7];
    float* out = (float*)d_out;

    char* p = (char*)d_ws;
    auto alloc = [&](size_t bytes) -> char* {
        char* r = p; p += (bytes + 255) & ~(size_t)255; return r;
    };
    float* u      = (float*)alloc(256 * 4);
    float* v      = (float*)alloc(256 * 4);
    unsigned short* wtb = (unsigned short*)alloc((size_t)128 * 256 * 2);
    float* si     = (float*)alloc((size_t)N_NODES * 4);
    float* sj     = (float*)alloc((size_t)N_NODES * 4);
    int*   deg    = (int*)alloc((size_t)N_NODES * 4);
    int*   offs   = (int*)alloc((size_t)N_NODES * 4);
    unsigned short* psb = (unsigned short*)alloc((size_t)N_NODES * OUT_DIM * 2);
    int*   hist_t = (int*)alloc((size_t)NBK * PBLK * 4);
    int*   bpre   = (int*)alloc((size_t)(NBK + 1) * 4);
    int*   off    = (int*)alloc((size_t)NBK * PBLK * 4);
    unsigned int* part = (unsigned int*)alloc((size_t)N_EDGES * 4);
    int2*  epack  = (int2*)alloc((size_t)N_EDGES * 8);

    kuv<<<1, 256, 0, stream>>>(fsW, fw, u, v);
    kwt<<<128, 256, 0, stream>>>(W, wtb);
    gemm_mfma<<<N_NODES / 32, 256, 0, stream>>>(x, wtb, u, v, psb, si, sj);
    khist1<<<PBLK, 256, 0, stream>>>(row, hist_t);
    kbscan<<<1, 1024, 0, stream>>>(hist_t, bpre);
    koff<<<NBK, PBLK, 0, stream>>>(hist_t, bpre, off);
    kpart1<<<PBLK, 256, 0, stream>>>(row, col, off, part);
    kpart2<<<NBK, 256, 0, stream>>>(part, bpre, si, sj, dia, fb, epack, offs, deg);
    kgather<<<N_NODES / 8, 256, 0, stream>>>(offs, deg, epack, psb, out);
}

// Round 14
// 214.935 us; speedup vs baseline: 1.3587x; 1.0384x over previous
//
#include <hip/hip_runtime.h>

#define N_NODES 100000
#define N_EDGES 1600000
#define IN_DIM 256
#define OUT_DIM 128
#define BROWS 100    // rows per bucket
#define NBK 1000     // buckets (100000/100)
#define PBLK 128     // partition blocks
#define EPB 12500    // edges per partition block

typedef __attribute__((ext_vector_type(4))) float f32x4;
typedef __attribute__((ext_vector_type(8))) short s16x8;

__device__ inline unsigned short f2bf(float f) {
    union { float f; unsigned int u; } a; a.f = f;
    unsigned int r = a.u + 0x7fffu + ((a.u >> 16) & 1u);
    return (unsigned short)(r >> 16);
}
__device__ inline float bf2f(unsigned short h) {
    union { unsigned int u; float f; } a; a.u = ((unsigned int)h) << 16;
    return a.f;
}

// ---------------- Kernel 0: fused prep: wt transpose + u/v ----------------
__global__ void kprep(const float* __restrict__ fsW, const float* __restrict__ fw,
                      const float* __restrict__ W, float* __restrict__ u,
                      float* __restrict__ v, unsigned short* __restrict__ wt) {
    if (blockIdx.x < 128) {
        int n = blockIdx.x;
        int k = threadIdx.x;
        wt[n * 256 + k] = f2bf(W[(size_t)k * 128 + n]);
    } else {
        __shared__ float wi[128], wj[128];
        int t = threadIdx.x;
        if (t < 128) wi[t] = fw[t]; else wj[t - 128] = fw[t];
        __syncthreads();
        const float* rowp = fsW + (size_t)t * OUT_DIM;
        float su = 0.f, sv = 0.f;
        for (int d = 0; d < 128; d += 4) {
            float4 a = *(const float4*)(rowp + d);
            su += a.x * wi[d] + a.y * wi[d + 1] + a.z * wi[d + 2] + a.w * wi[d + 3];
            sv += a.x * wj[d] + a.y * wj[d + 1] + a.z * wj[d + 2] + a.w * wj[d + 3];
        }
        u[t] = su; v[t] = sv;
    }
}

// ------- Kernel 1: MFMA GEMM (round-12 skeleton) + coalesced C-write + B prefetch -------
// Block: 256 thr (4 waves). Tile: 64 nodes x 128 cols, K in 2 phases of 128.
__global__ __launch_bounds__(256) void gemm_mfma(
        const float* __restrict__ x, const unsigned short* __restrict__ wt,
        const float* __restrict__ u, const float* __restrict__ v,
        unsigned short* __restrict__ psb, float* __restrict__ si, float* __restrict__ sj) {
    __shared__ unsigned short xa[64 * 136];    // 17408 B; reused as C-tile at the end

    const int t = threadIdx.x;
    const int wave = t >> 6, lane = t & 63;
    const int l15 = lane & 15, lhi = lane >> 4;
    const int row = t >> 2, quad = t & 3;      // staging roles
    const int brow = blockIdx.x * 64;
    const int gnode = brow + row;
    const bool valid = gnode < N_NODES;

    f32x4 acc[4][2];
#pragma unroll
    for (int mi = 0; mi < 4; ++mi)
#pragma unroll
        for (int ni = 0; ni < 2; ++ni) acc[mi][ni] = (f32x4){0.f, 0.f, 0.f, 0.f};
    float su = 0.f, sv = 0.f;

#pragma unroll
    for (int ph = 0; ph < 2; ++ph) {
        // ---- stage x half-tile (64 nodes x 128 k), f32 -> bf16, + si/sj partials ----
        {
            const float* xp = x + (size_t)gnode * IN_DIM + ph * 128 + quad * 32;
            const float* up = u + ph * 128 + quad * 32;
            const float* vp = v + ph * 128 + quad * 32;
#pragma unroll
            for (int cc = 0; cc < 4; ++cc) {
                float4 a0 = make_float4(0.f, 0.f, 0.f, 0.f), a1 = a0;
                if (valid) {
                    a0 = ((const float4*)xp)[cc * 2];
                    a1 = ((const float4*)xp)[cc * 2 + 1];
                    float4 u0 = ((const float4*)up)[cc * 2], u1 = ((const float4*)up)[cc * 2 + 1];
                    float4 v0 = ((const float4*)vp)[cc * 2], v1 = ((const float4*)vp)[cc * 2 + 1];
                    su = fmaf(a0.x, u0.x, su); su = fmaf(a0.y, u0.y, su);
                    su = fmaf(a0.z, u0.z, su); su = fmaf(a0.w, u0.w, su);
                    su = fmaf(a1.x, u1.x, su); su = fmaf(a1.y, u1.y, su);
                    su = fmaf(a1.z, u1.z, su); su = fmaf(a1.w, u1.w, su);
                    sv = fmaf(a0.x, v0.x, sv); sv = fmaf(a0.y, v0.y, sv);
                    sv = fmaf(a0.z, v0.z, sv); sv = fmaf(a0.w, v0.w, sv);
                    sv = fmaf(a1.x, v1.x, sv); sv = fmaf(a1.y, v1.y, sv);
                    sv = fmaf(a1.z, v1.z, sv); sv = fmaf(a1.w, v1.w, sv);
                }
                union { unsigned short h[8]; uint4 q; } pk;
                pk.h[0] = f2bf(a0.x); pk.h[1] = f2bf(a0.y); pk.h[2] = f2bf(a0.z); pk.h[3] = f2bf(a0.w);
                pk.h[4] = f2bf(a1.x); pk.h[5] = f2bf(a1.y); pk.h[6] = f2bf(a1.z); pk.h[7] = f2bf(a1.w);
                *(uint4*)&xa[row * 136 + quad * 32 + cc * 8] = pk.q;
            }
        }
        __syncthreads();

        // ---- hoist all 8 B-fragments of this phase into registers (deep MLP) ----
        {
            const unsigned short* wb0 = wt + (size_t)(wave * 32 + l15) * IN_DIM + ph * 128 + lhi * 8;
            s16x8 bfr[4][2];
#pragma unroll
            for (int ks = 0; ks < 4; ++ks) {
                bfr[ks][0] = *(const s16x8*)(wb0 + ks * 32);
                bfr[ks][1] = *(const s16x8*)(wb0 + (size_t)16 * IN_DIM + ks * 32);
            }
#pragma unroll
            for (int ks = 0; ks < 4; ++ks) {
                const int k0 = ks * 32 + lhi * 8;
                s16x8 afr[4];
#pragma unroll
                for (int mi = 0; mi < 4; ++mi)
                    afr[mi] = *(const s16x8*)&xa[(mi * 16 + l15) * 136 + k0];
#pragma unroll
                for (int mi = 0; mi < 4; ++mi)
#pragma unroll
                    for (int ni = 0; ni < 2; ++ni)
                        acc[mi][ni] = __builtin_amdgcn_mfma_f32_16x16x32_bf16(
                            afr[mi], bfr[ks][ni], acc[mi][ni], 0, 0, 0);
            }
        }
        __syncthreads();
    }

    su += __shfl_xor(su, 1); su += __shfl_xor(su, 2);
    sv += __shfl_xor(sv, 1); sv += __shfl_xor(sv, 2);
    if (quad == 0 && valid) { si[gnode] = su; sj[gnode] = sv; }

    // ---- C-write: fragments -> LDS (bf16, linear [64][128]) -> coalesced global ----
    unsigned short* cl = xa;   // reuse (16 KB needed, 17408 available)
#pragma unroll
    for (int mi = 0; mi < 4; ++mi)
#pragma unroll
        for (int ni = 0; ni < 2; ++ni) {
            const int colb = wave * 32 + ni * 16 + l15;
#pragma unroll
            for (int j = 0; j < 4; ++j)
                cl[(mi * 16 + lhi * 4 + j) * 128 + colb] = f2bf(acc[mi][ni][j]);
        }
    __syncthreads();
    {
        const int rl = t >> 2;              // 0..63
        const int cb = (t & 3) * 32;        // col base
        if (brow + rl < N_NODES) {
            const uint4* src = (const uint4*)&cl[rl * 128 + cb];
            uint4* dst = (uint4*)&psb[(size_t)(brow + rl) * OUT_DIM + cb];
            dst[0] = src[0]; dst[1] = src[1]; dst[2] = src[2]; dst[3] = src[3];
        }
    }
}

// ------- Kernel 2: per-(block,bucket) histogram -------
__global__ __launch_bounds__(256) void khist1(const int* __restrict__ row,
                                              int* __restrict__ hist_t) {
    __shared__ int h[NBK];
    const int t = threadIdx.x, blk = blockIdx.x;
    for (int b = t; b < NBK; b += 256) h[b] = 0;
    __syncthreads();
    const int e0 = blk * EPB;
    for (int i = t; i < EPB; i += 256) {
        int r = row[e0 + i];
        atomicAdd(&h[r / BROWS], 1);
    }
    __syncthreads();
    for (int b = t; b < NBK; b += 256)
        hist_t[b * PBLK + blk] = h[b];
}

// ------- Kernel 3: bucket sums + exclusive scan (single block) -------
__global__ __launch_bounds__(1024) void kbscan(const int* __restrict__ hist_t,
                                               int* __restrict__ bpre) {
    __shared__ int s[1024];
    const int t = threadIdx.x;
    int v = 0;
    if (t < NBK) {
        const int* hp = hist_t + t * PBLK;
        for (int k = 0; k < PBLK; ++k) v += hp[k];
    }
    s[t] = v;
    __syncthreads();
    for (int off = 1; off < 1024; off <<= 1) {
        int nv = (t >= off) ? s[t - off] : 0;
        __syncthreads();
        s[t] += nv;
        __syncthreads();
    }
    if (t < NBK) bpre[t] = s[t] - v;
    if (t == 1023) bpre[NBK] = s[1023];
}

// ------- Kernel 4: per-(bucket,block) offsets -------
__global__ __launch_bounds__(128) void koff(const int* __restrict__ hist_t,
                                            const int* __restrict__ bpre,
                                            int* __restrict__ off) {
    const int b = blockIdx.x, t = threadIdx.x;
    const int lane = t & 63, w = t >> 6;
    int v = hist_t[b * PBLK + t];
    int s = v;
#pragma unroll
    for (int o = 1; o < 64; o <<= 1) { int tt = __shfl_up(s, o); if (lane >= o) s += tt; }
    __shared__ int ws2[2];
    if (lane == 63) ws2[w] = s;
    __syncthreads();
    int base = (w == 1) ? ws2[0] : 0;
    off[b * PBLK + t] = bpre[b] + base + (s - v);
}

// ------- Kernel 5: partition edges into bucket-contiguous runs (packed 4B) -------
__global__ __launch_bounds__(256) void kpart1(const int* __restrict__ row,
                                              const int* __restrict__ col,
                                              const int* __restrict__ off,
                                              unsigned int* __restrict__ part) {
    __shared__ int cur[NBK];
    const int t = threadIdx.x, blk = blockIdx.x;
    for (int b = t; b < NBK; b += 256) cur[b] = off[b * PBLK + blk];
    __syncthreads();
    const int e0 = blk * EPB;
    for (int i = t; i < EPB; i += 256) {
        int r = row[e0 + i], c = col[e0 + i];
        int b = r / BROWS;
        int rl = r - b * BROWS;
        int pos = atomicAdd(&cur[b], 1);
        part[pos] = ((unsigned)rl << 17) | (unsigned)c;
    }
}

// ------- Kernel 6: per-bucket row-histogram + local scan -> offs/deg, CSR + value -------
__global__ __launch_bounds__(256) void kpart2(const unsigned int* __restrict__ part,
                                              const int* __restrict__ bpre,
                                              const float* __restrict__ si,
                                              const float* __restrict__ sj,
                                              const float* __restrict__ dia,
                                              const float* __restrict__ fb,
                                              int2* __restrict__ epack,
                                              int* __restrict__ offs,
                                              int* __restrict__ deg) {
    __shared__ int cnt[BROWS];
    __shared__ int cur[BROWS];
    __shared__ float sil[BROWS], dial[BROWS];
    __shared__ int wtot[4];
    const int b = blockIdx.x, t = threadIdx.x;
    const int rbase = b * BROWS;
    if (t < BROWS) {
        cnt[t] = 0;
        sil[t] = si[rbase + t];
        dial[t] = dia[rbase + t];
    }
    __syncthreads();
    const int bstart = bpre[b], bend = bpre[b + 1];
    for (int e = bstart + t; e < bend; e += 256)
        atomicAdd(&cnt[part[e] >> 17], 1);
    __syncthreads();
    {
        int vv = (t < BROWS) ? cnt[t] : 0;
        int lane = t & 63, w = t >> 6;
        int s = vv;
#pragma unroll
        for (int o = 1; o < 64; o <<= 1) { int tt = __shfl_up(s, o); if (lane >= o) s += tt; }
        if (lane == 63) wtot[w] = s;
        __syncthreads();
        int base = 0;
        for (int k = 0; k < w; ++k) base += wtot[k];
        int excl = base + s - vv;
        if (t < BROWS) {
            cur[t] = bstart + excl;
            offs[rbase + t] = bstart + excl;
            deg[rbase + t] = vv;
        }
    }
    __syncthreads();
    const float fbv = fb[0];
    for (int e = bstart + t; e < bend; e += 256) {
        unsigned pk = part[e];
        int rl = (int)(pk >> 17);
        int c = (int)(pk & 0x1FFFFu);
        float tval = sil[rl] + sj[c] + fbv;
        float sg = 1.f / (1.f + expf(-tval));
        float l2 = log2f(dial[rl] * dia[c]);
        float val = exp2f(-sg * l2);
        int pos = atomicAdd(&cur[rl], 1);
        epack[pos] = make_int2(c, __float_as_int(val));
    }
}

// ------- Kernel 7: per-node gather-accumulate + ReLU (round-4 proven) -------
__global__ __launch_bounds__(256) void kgather(
        const int* __restrict__ offs, const int* __restrict__ deg,
        const int2* __restrict__ epack,
        const unsigned short* __restrict__ psb, float* __restrict__ out) {
    int lane = threadIdx.x & 31;
    int node = blockIdx.x * 8 + (threadIdx.x >> 5);
    if (node >= N_NODES) return;
    int start = offs[node], d = deg[node];
    const int2* ep = epack + start;
    float a0 = 0.f, a1 = 0.f, a2 = 0.f, a3 = 0.f;
    int k = 0;
    for (; k + 2 <= d; k += 2) {
        int2 e0 = ep[k], e1 = ep[k + 1];
        float v0 = __int_as_float(e0.y), v1 = __int_as_float(e1.y);
        ushort4 p0 = *(const ushort4*)&psb[(size_t)e0.x * OUT_DIM + lane * 4];
        ushort4 p1 = *(const ushort4*)&psb[(size_t)e1.x * OUT_DIM + lane * 4];
        a0 = fmaf(v0, bf2f(p0.x), a0); a0 = fmaf(v1, bf2f(p1.x), a0);
        a1 = fmaf(v0, bf2f(p0.y), a1); a1 = fmaf(v1, bf2f(p1.y), a1);
        a2 = fmaf(v0, bf2f(p0.z), a2); a2 = fmaf(v1, bf2f(p1.z), a2);
        a3 = fmaf(v0, bf2f(p0.w), a3); a3 = fmaf(v1, bf2f(p1.w), a3);
    }
    if (k < d) {
        int2 e0 = ep[k];
        float v0 = __int_as_float(e0.y);
        ushort4 p0 = *(const ushort4*)&psb[(size_t)e0.x * OUT_DIM + lane * 4];
        a0 = fmaf(v0, bf2f(p0.x), a0);
        a1 = fmaf(v0, bf2f(p0.y), a1);
        a2 = fmaf(v0, bf2f(p0.z), a2);
        a3 = fmaf(v0, bf2f(p0.w), a3);
    }
    float4 o;
    o.x = fmaxf(a0, 0.f); o.y = fmaxf(a1, 0.f);
    o.z = fmaxf(a2, 0.f); o.w = fmaxf(a3, 0.f);
    *(float4*)&out[(size_t)node * OUT_DIM + lane * 4] = o;
}

extern "C" void kernel_launch(void* const* d_in, const int* in_sizes, int n_in,
                              void* d_out, int out_size, void* d_ws, size_t ws_size,
                              hipStream_t stream) {
    const float* x   = (const float*)d_in[0];
    const float* W   = (const float*)d_in[1];
    const float* fsW = (const float*)d_in[2];
    const float* fw  = (const float*)d_in[3];
    const float* fb  = (const float*)d_in[4];
    const float* dia = (const float*)d_in[5];
    const int*   row = (const int*)d_in[6];
    const int*   col = (const int*)d_in[7];
    float* out = (float*)d_out;

    char* p = (char*)d_ws;
    auto alloc = [&](size_t bytes) -> char* {
        char* r = p; p += (bytes + 255) & ~(size_t)255; return r;
    };
    float* u      = (float*)alloc(256 * 4);
    float* v      = (float*)alloc(256 * 4);
    unsigned short* wtb = (unsigned short*)alloc((size_t)128 * 256 * 2);
    float* si     = (float*)alloc((size_t)N_NODES * 4);
    float* sj     = (float*)alloc((size_t)N_NODES * 4);
    int*   deg    = (int*)alloc((size_t)N_NODES * 4);
    int*   offs   = (int*)alloc((size_t)N_NODES * 4);
    unsigned short* psb = (unsigned short*)alloc((size_t)N_NODES * OUT_DIM * 2);
    int*   hist_t = (int*)alloc((size_t)NBK * PBLK * 4);
    int*   bpre   = (int*)alloc((size_t)(NBK + 1) * 4);
    int*   off    = (int*)alloc((size_t)NBK * PBLK * 4);
    unsigned int* part = (unsigned int*)alloc((size_t)N_EDGES * 4);
    int2*  epack  = (int2*)alloc((size_t)N_EDGES * 8);

    kprep<<<129, 256, 0, stream>>>(fsW, fw, W, u, v, wtb);
    gemm_mfma<<<(N_NODES + 63) / 64, 256, 0, stream>>>(x, wtb, u, v, psb, si, sj);
    khist1<<<PBLK, 256, 0, stream>>>(row, hist_t);
    kbscan<<<1, 1024, 0, stream>>>(hist_t, bpre);
    koff<<<NBK, PBLK, 0, stream>>>(hist_t, bpre, off);
    kpart1<<<PBLK, 256, 0, stream>>>(row, col, off, part);
    kpart2<<<NBK, 256, 0, stream>>>(part, bpre, si, sj, dia, fb, epack, offs, deg);
    kgather<<<N_NODES / 8, 256, 0, stream>>>(offs, deg, epack, psb, out);
}

// Round 15
// 207.212 us; speedup vs baseline: 1.4093x; 1.0373x over previous
//
#include <hip/hip_runtime.h>

#define N_NODES 100000
#define N_EDGES 1600000
#define IN_DIM 256
#define OUT_DIM 128
#define BROWS 100    // rows per bucket
#define NBK 1000     // buckets (100000/100)
#define PBLK 128     // partition blocks
#define EPB 12500    // edges per partition block

typedef __attribute__((ext_vector_type(4))) float f32x4;
typedef __attribute__((ext_vector_type(8))) short s16x8;

__device__ inline unsigned short f2bf(float f) {
    union { float f; unsigned int u; } a; a.f = f;
    unsigned int r = a.u + 0x7fffu + ((a.u >> 16) & 1u);
    return (unsigned short)(r >> 16);
}
__device__ inline float bf2f(unsigned short h) {
    union { unsigned int u; float f; } a; a.u = ((unsigned int)h) << 16;
    return a.f;
}

// ---- Kernel 0 (fused): wt transpose + per-(block,bucket) histogram + u/v ----
__global__ __launch_bounds__(256) void kprep(
        const float* __restrict__ fsW, const float* __restrict__ fw,
        const float* __restrict__ W, const int* __restrict__ row,
        float* __restrict__ u, float* __restrict__ v,
        unsigned short* __restrict__ wt, int* __restrict__ hist_t) {
    __shared__ int h[NBK];
    __shared__ float wi[128], wj[128];
    const int t = threadIdx.x, blk = blockIdx.x;
    if (blk < PBLK) {
        // wt transpose piece (n = blk)
        wt[blk * 256 + t] = f2bf(W[(size_t)t * 128 + blk]);
        // histogram piece
        for (int b = t; b < NBK; b += 256) h[b] = 0;
        __syncthreads();
        const int e0 = blk * EPB;
        for (int i = t; i < EPB; i += 256)
            atomicAdd(&h[row[e0 + i] / BROWS], 1);
        __syncthreads();
        for (int b = t; b < NBK; b += 256)
            hist_t[b * PBLK + blk] = h[b];
    } else {
        if (t < 128) wi[t] = fw[t]; else wj[t - 128] = fw[t];
        __syncthreads();
        const float* rowp = fsW + (size_t)t * OUT_DIM;
        float su = 0.f, sv = 0.f;
        for (int d = 0; d < 128; d += 4) {
            float4 a = *(const float4*)(rowp + d);
            su += a.x * wi[d] + a.y * wi[d + 1] + a.z * wi[d + 2] + a.w * wi[d + 3];
            sv += a.x * wj[d] + a.y * wj[d + 1] + a.z * wj[d + 2] + a.w * wj[d + 3];
        }
        u[t] = su; v[t] = sv;
    }
}

// ------- Kernel 1: MFMA GEMM + block-uniform fast path + coalesced C-write -------
__global__ __launch_bounds__(256) void gemm_mfma(
        const float* __restrict__ x, const unsigned short* __restrict__ wt,
        const float* __restrict__ u, const float* __restrict__ v,
        unsigned short* __restrict__ psb, float* __restrict__ si, float* __restrict__ sj) {
    __shared__ unsigned short xa[64 * 136];    // 17408 B; reused as C-tile at the end

    const int t = threadIdx.x;
    const int wave = t >> 6, lane = t & 63;
    const int l15 = lane & 15, lhi = lane >> 4;
    const int row = t >> 2, quad = t & 3;
    const int brow = blockIdx.x * 64;
    const int gnode = brow + row;
    const bool fullblk = (brow + 64 <= N_NODES);   // uniform across block
    const bool valid = gnode < N_NODES;

    f32x4 acc[4][2];
#pragma unroll
    for (int mi = 0; mi < 4; ++mi)
#pragma unroll
        for (int ni = 0; ni < 2; ++ni) acc[mi][ni] = (f32x4){0.f, 0.f, 0.f, 0.f};
    float su = 0.f, sv = 0.f;

#pragma unroll
    for (int ph = 0; ph < 2; ++ph) {
        const float* xp = x + (size_t)gnode * IN_DIM + ph * 128 + quad * 32;
        const float* up = u + ph * 128 + quad * 32;
        const float* vp = v + ph * 128 + quad * 32;
        if (fullblk) {
            // hot path: unconditional, batchable loads
#pragma unroll
            for (int cc = 0; cc < 4; ++cc) {
                float4 a0 = ((const float4*)xp)[cc * 2];
                float4 a1 = ((const float4*)xp)[cc * 2 + 1];
                float4 u0 = ((const float4*)up)[cc * 2], u1 = ((const float4*)up)[cc * 2 + 1];
                float4 v0 = ((const float4*)vp)[cc * 2], v1 = ((const float4*)vp)[cc * 2 + 1];
                su = fmaf(a0.x, u0.x, su); su = fmaf(a0.y, u0.y, su);
                su = fmaf(a0.z, u0.z, su); su = fmaf(a0.w, u0.w, su);
                su = fmaf(a1.x, u1.x, su); su = fmaf(a1.y, u1.y, su);
                su = fmaf(a1.z, u1.z, su); su = fmaf(a1.w, u1.w, su);
                sv = fmaf(a0.x, v0.x, sv); sv = fmaf(a0.y, v0.y, sv);
                sv = fmaf(a0.z, v0.z, sv); sv = fmaf(a0.w, v0.w, sv);
                sv = fmaf(a1.x, v1.x, sv); sv = fmaf(a1.y, v1.y, sv);
                sv = fmaf(a1.z, v1.z, sv); sv = fmaf(a1.w, v1.w, sv);
                union { unsigned short h[8]; uint4 q; } pk;
                pk.h[0] = f2bf(a0.x); pk.h[1] = f2bf(a0.y); pk.h[2] = f2bf(a0.z); pk.h[3] = f2bf(a0.w);
                pk.h[4] = f2bf(a1.x); pk.h[5] = f2bf(a1.y); pk.h[6] = f2bf(a1.z); pk.h[7] = f2bf(a1.w);
                *(uint4*)&xa[row * 136 + quad * 32 + cc * 8] = pk.q;
            }
        } else {
#pragma unroll
            for (int cc = 0; cc < 4; ++cc) {
                float4 a0 = make_float4(0.f, 0.f, 0.f, 0.f), a1 = a0;
                if (valid) {
                    a0 = ((const float4*)xp)[cc * 2];
                    a1 = ((const float4*)xp)[cc * 2 + 1];
                    float4 u0 = ((const float4*)up)[cc * 2], u1 = ((const float4*)up)[cc * 2 + 1];
                    float4 v0 = ((const float4*)vp)[cc * 2], v1 = ((const float4*)vp)[cc * 2 + 1];
                    su = fmaf(a0.x, u0.x, su); su = fmaf(a0.y, u0.y, su);
                    su = fmaf(a0.z, u0.z, su); su = fmaf(a0.w, u0.w, su);
                    su = fmaf(a1.x, u1.x, su); su = fmaf(a1.y, u1.y, su);
                    su = fmaf(a1.z, u1.z, su); su = fmaf(a1.w, u1.w, su);
                    sv = fmaf(a0.x, v0.x, sv); sv = fmaf(a0.y, v0.y, sv);
                    sv = fmaf(a0.z, v0.z, sv); sv = fmaf(a0.w, v0.w, sv);
                    sv = fmaf(a1.x, v1.x, sv); sv = fmaf(a1.y, v1.y, sv);
                    sv = fmaf(a1.z, v1.z, sv); sv = fmaf(a1.w, v1.w, sv);
                }
                union { unsigned short h[8]; uint4 q; } pk;
                pk.h[0] = f2bf(a0.x); pk.h[1] = f2bf(a0.y); pk.h[2] = f2bf(a0.z); pk.h[3] = f2bf(a0.w);
                pk.h[4] = f2bf(a1.x); pk.h[5] = f2bf(a1.y); pk.h[6] = f2bf(a1.z); pk.h[7] = f2bf(a1.w);
                *(uint4*)&xa[row * 136 + quad * 32 + cc * 8] = pk.q;
            }
        }
        __syncthreads();

        // ---- hoisted B-fragments (deep MLP) + 4 K-steps of MFMA ----
        {
            const unsigned short* wb0 = wt + (size_t)(wave * 32 + l15) * IN_DIM + ph * 128 + lhi * 8;
            s16x8 bfr[4][2];
#pragma unroll
            for (int ks = 0; ks < 4; ++ks) {
                bfr[ks][0] = *(const s16x8*)(wb0 + ks * 32);
                bfr[ks][1] = *(const s16x8*)(wb0 + (size_t)16 * IN_DIM + ks * 32);
            }
#pragma unroll
            for (int ks = 0; ks < 4; ++ks) {
                const int k0 = ks * 32 + lhi * 8;
                s16x8 afr[4];
#pragma unroll
                for (int mi = 0; mi < 4; ++mi)
                    afr[mi] = *(const s16x8*)&xa[(mi * 16 + l15) * 136 + k0];
#pragma unroll
                for (int mi = 0; mi < 4; ++mi)
#pragma unroll
                    for (int ni = 0; ni < 2; ++ni)
                        acc[mi][ni] = __builtin_amdgcn_mfma_f32_16x16x32_bf16(
                            afr[mi], bfr[ks][ni], acc[mi][ni], 0, 0, 0);
            }
        }
        __syncthreads();
    }

    su += __shfl_xor(su, 1); su += __shfl_xor(su, 2);
    sv += __shfl_xor(sv, 1); sv += __shfl_xor(sv, 2);
    if (quad == 0 && valid) { si[gnode] = su; sj[gnode] = sv; }

    // ---- C-write: fragments -> LDS (bf16, [64][128]) -> coalesced global ----
    unsigned short* cl = xa;
#pragma unroll
    for (int mi = 0; mi < 4; ++mi)
#pragma unroll
        for (int ni = 0; ni < 2; ++ni) {
            const int colb = wave * 32 + ni * 16 + l15;
#pragma unroll
            for (int j = 0; j < 4; ++j)
                cl[(mi * 16 + lhi * 4 + j) * 128 + colb] = f2bf(acc[mi][ni][j]);
        }
    __syncthreads();
    {
        const int rl = t >> 2;
        const int cb = (t & 3) * 32;
        if (brow + rl < N_NODES) {
            const uint4* src = (const uint4*)&cl[rl * 128 + cb];
            uint4* dst = (uint4*)&psb[(size_t)(brow + rl) * OUT_DIM + cb];
            dst[0] = src[0]; dst[1] = src[1]; dst[2] = src[2]; dst[3] = src[3];
        }
    }
}

// ------- Kernel 3: bucket sums + exclusive scan (single block) -------
__global__ __launch_bounds__(1024) void kbscan(const int* __restrict__ hist_t,
                                               int* __restrict__ bpre) {
    __shared__ int s[1024];
    const int t = threadIdx.x;
    int v = 0;
    if (t < NBK) {
        const int* hp = hist_t + t * PBLK;
        for (int k = 0; k < PBLK; ++k) v += hp[k];
    }
    s[t] = v;
    __syncthreads();
    for (int off = 1; off < 1024; off <<= 1) {
        int nv = (t >= off) ? s[t - off] : 0;
        __syncthreads();
        s[t] += nv;
        __syncthreads();
    }
    if (t < NBK) bpre[t] = s[t] - v;
    if (t == 1023) bpre[NBK] = s[1023];
}

// ------- Kernel 4: per-(bucket,block) offsets -------
__global__ __launch_bounds__(128) void koff(const int* __restrict__ hist_t,
                                            const int* __restrict__ bpre,
                                            int* __restrict__ off) {
    const int b = blockIdx.x, t = threadIdx.x;
    const int lane = t & 63, w = t >> 6;
    int v = hist_t[b * PBLK + t];
    int s = v;
#pragma unroll
    for (int o = 1; o < 64; o <<= 1) { int tt = __shfl_up(s, o); if (lane >= o) s += tt; }
    __shared__ int ws2[2];
    if (lane == 63) ws2[w] = s;
    __syncthreads();
    int base = (w == 1) ? ws2[0] : 0;
    off[b * PBLK + t] = bpre[b] + base + (s - v);
}

// ------- Kernel 5: partition edges into bucket-contiguous runs (packed 4B) -------
__global__ __launch_bounds__(256) void kpart1(const int* __restrict__ row,
                                              const int* __restrict__ col,
                                              const int* __restrict__ off,
                                              unsigned int* __restrict__ part) {
    __shared__ int cur[NBK];
    const int t = threadIdx.x, blk = blockIdx.x;
    for (int b = t; b < NBK; b += 256) cur[b] = off[b * PBLK + blk];
    __syncthreads();
    const int e0 = blk * EPB;
    for (int i = t; i < EPB; i += 256) {
        int r = row[e0 + i], c = col[e0 + i];
        int b = r / BROWS;
        int rl = r - b * BROWS;
        int pos = atomicAdd(&cur[b], 1);
        part[pos] = ((unsigned)rl << 17) | (unsigned)c;
    }
}

// ------- Kernel 6: per-bucket row-histogram + local scan -> offs/deg, CSR + value -------
__global__ __launch_bounds__(256) void kpart2(const unsigned int* __restrict__ part,
                                              const int* __restrict__ bpre,
                                              const float* __restrict__ si,
                                              const float* __restrict__ sj,
                                              const float* __restrict__ dia,
                                              const float* __restrict__ fb,
                                              int2* __restrict__ epack,
                                              int* __restrict__ offs,
                                              int* __restrict__ deg) {
    __shared__ int cnt[BROWS];
    __shared__ int cur[BROWS];
    __shared__ float sil[BROWS], dial[BROWS];
    __shared__ int wtot[4];
    const int b = blockIdx.x, t = threadIdx.x;
    const int rbase = b * BROWS;
    if (t < BROWS) {
        cnt[t] = 0;
        sil[t] = si[rbase + t];
        dial[t] = dia[rbase + t];
    }
    __syncthreads();
    const int bstart = bpre[b], bend = bpre[b + 1];
    for (int e = bstart + t; e < bend; e += 256)
        atomicAdd(&cnt[part[e] >> 17], 1);
    __syncthreads();
    {
        int vv = (t < BROWS) ? cnt[t] : 0;
        int lane = t & 63, w = t >> 6;
        int s = vv;
#pragma unroll
        for (int o = 1; o < 64; o <<= 1) { int tt = __shfl_up(s, o); if (lane >= o) s += tt; }
        if (lane == 63) wtot[w] = s;
        __syncthreads();
        int base = 0;
        for (int k = 0; k < w; ++k) base += wtot[k];
        int excl = base + s - vv;
        if (t < BROWS) {
            cur[t] = bstart + excl;
            offs[rbase + t] = bstart + excl;
            deg[rbase + t] = vv;
        }
    }
    __syncthreads();
    const float fbv = fb[0];
    for (int e = bstart + t; e < bend; e += 256) {
        unsigned pk = part[e];
        int rl = (int)(pk >> 17);
        int c = (int)(pk & 0x1FFFFu);
        float tval = sil[rl] + sj[c] + fbv;
        float sg = 1.f / (1.f + expf(-tval));
        float l2 = log2f(dial[rl] * dia[c]);
        float val = exp2f(-sg * l2);
        int pos = atomicAdd(&cur[rl], 1);
        epack[pos] = make_int2(c, __float_as_int(val));
    }
}

// ------- Kernel 7: per-node gather-accumulate + ReLU, 4-edge deep MLP -------
__global__ __launch_bounds__(256) void kgather(
        const int* __restrict__ offs, const int* __restrict__ deg,
        const int2* __restrict__ epack,
        const unsigned short* __restrict__ psb, float* __restrict__ out) {
    int lane = threadIdx.x & 31;
    int node = blockIdx.x * 8 + (threadIdx.x >> 5);
    if (node >= N_NODES) return;
    int start = offs[node], d = deg[node];
    const int2* ep = epack + start;
    float a0 = 0.f, a1 = 0.f, a2 = 0.f, a3 = 0.f;
    int k = 0;
    for (; k + 4 <= d; k += 4) {
        int2 e0 = ep[k], e1 = ep[k + 1], e2 = ep[k + 2], e3 = ep[k + 3];
        ushort4 p0 = *(const ushort4*)&psb[(size_t)e0.x * OUT_DIM + lane * 4];
        ushort4 p1 = *(const ushort4*)&psb[(size_t)e1.x * OUT_DIM + lane * 4];
        ushort4 p2 = *(const ushort4*)&psb[(size_t)e2.x * OUT_DIM + lane * 4];
        ushort4 p3 = *(const ushort4*)&psb[(size_t)e3.x * OUT_DIM + lane * 4];
        float v0 = __int_as_float(e0.y), v1 = __int_as_float(e1.y);
        float v2 = __int_as_float(e2.y), v3 = __int_as_float(e3.y);
        a0 = fmaf(v0, bf2f(p0.x), a0); a1 = fmaf(v0, bf2f(p0.y), a1);
        a2 = fmaf(v0, bf2f(p0.z), a2); a3 = fmaf(v0, bf2f(p0.w), a3);
        a0 = fmaf(v1, bf2f(p1.x), a0); a1 = fmaf(v1, bf2f(p1.y), a1);
        a2 = fmaf(v1, bf2f(p1.z), a2); a3 = fmaf(v1, bf2f(p1.w), a3);
        a0 = fmaf(v2, bf2f(p2.x), a0); a1 = fmaf(v2, bf2f(p2.y), a1);
        a2 = fmaf(v2, bf2f(p2.z), a2); a3 = fmaf(v2, bf2f(p2.w), a3);
        a0 = fmaf(v3, bf2f(p3.x), a0); a1 = fmaf(v3, bf2f(p3.y), a1);
        a2 = fmaf(v3, bf2f(p3.z), a2); a3 = fmaf(v3, bf2f(p3.w), a3);
    }
    for (; k < d; ++k) {
        int2 e0 = ep[k];
        float v0 = __int_as_float(e0.y);
        ushort4 p0 = *(const ushort4*)&psb[(size_t)e0.x * OUT_DIM + lane * 4];
        a0 = fmaf(v0, bf2f(p0.x), a0);
        a1 = fmaf(v0, bf2f(p0.y), a1);
        a2 = fmaf(v0, bf2f(p0.z), a2);
        a3 = fmaf(v0, bf2f(p0.w), a3);
    }
    float4 o;
    o.x = fmaxf(a0, 0.f); o.y = fmaxf(a1, 0.f);
    o.z = fmaxf(a2, 0.f); o.w = fmaxf(a3, 0.f);
    *(float4*)&out[(size_t)node * OUT_DIM + lane * 4] = o;
}

extern "C" void kernel_launch(void* const* d_in, const int* in_sizes, int n_in,
                              void* d_out, int out_size, void* d_ws, size_t ws_size,
                              hipStream_t stream) {
    const float* x   = (const float*)d_in[0];
    const float* W   = (const float*)d_in[1];
    const float* fsW = (const float*)d_in[2];
    const float* fw  = (const float*)d_in[3];
    const float* fb  = (const float*)d_in[4];
    const float* dia = (const float*)d_in[5];
    const int*   row = (const int*)d_in[6];
    const int*   col = (const int*)d_in[7];
    float* out = (float*)d_out;

    char* p = (char*)d_ws;
    auto alloc = [&](size_t bytes) -> char* {
        char* r = p; p += (bytes + 255) & ~(size_t)255; return r;
    };
    float* u      = (float*)alloc(256 * 4);
    float* v      = (float*)alloc(256 * 4);
    unsigned short* wtb = (unsigned short*)alloc((size_t)128 * 256 * 2);
    float* si     = (float*)alloc((size_t)N_NODES * 4);
    float* sj     = (float*)alloc((size_t)N_NODES * 4);
    int*   deg    = (int*)alloc((size_t)N_NODES * 4);
    int*   offs   = (int*)alloc((size_t)N_NODES * 4);
    unsigned short* psb = (unsigned short*)alloc((size_t)N_NODES * OUT_DIM * 2);
    int*   hist_t = (int*)alloc((size_t)NBK * PBLK * 4);
    int*   bpre   = (int*)alloc((size_t)(NBK + 1) * 4);
    int*   off    = (int*)alloc((size_t)NBK * PBLK * 4);
    unsigned int* part = (unsigned int*)alloc((size_t)N_EDGES * 4);
    int2*  epack  = (int2*)alloc((size_t)N_EDGES * 8);

    kprep<<<PBLK + 1, 256, 0, stream>>>(fsW, fw, W, row, u, v, wtb, hist_t);
    gemm_mfma<<<(N_NODES + 63) / 64, 256, 0, stream>>>(x, wtb, u, v, psb, si, sj);
    kbscan<<<1, 1024, 0, stream>>>(hist_t, bpre);
    koff<<<NBK, PBLK, 0, stream>>>(hist_t, bpre, off);
    kpart1<<<PBLK, 256, 0, stream>>>(row, col, off, part);
    kpart2<<<NBK, 256, 0, stream>>>(part, bpre, si, sj, dia, fb, epack, offs, deg);
    kgather<<<N_NODES / 8, 256, 0, stream>>>(offs, deg, epack, psb, out);
}

// Round 16
// 200.927 us; speedup vs baseline: 1.4534x; 1.0313x over previous
//
#include <hip/hip_runtime.h>

#define N_NODES 100000
#define N_EDGES 1600000
#define IN_DIM 256
#define OUT_DIM 128
#define BROWS 100    // rows per bucket
#define NBK 1000     // buckets (100000/100)
#define PBLK 128     // partition blocks
#define EPB 12500    // edges per partition block

typedef __attribute__((ext_vector_type(4))) float f32x4;
typedef __attribute__((ext_vector_type(8))) short s16x8;

__device__ inline unsigned short f2bf(float f) {
    union { float f; unsigned int u; } a; a.f = f;
    unsigned int r = a.u + 0x7fffu + ((a.u >> 16) & 1u);
    return (unsigned short)(r >> 16);
}
__device__ inline float bf2f(unsigned short h) {
    union { unsigned int u; float f; } a; a.u = ((unsigned int)h) << 16;
    return a.f;
}

// ---- Kernel 0 (fused): wt transpose + per-(block,bucket) histogram + u/v ----
__global__ __launch_bounds__(256) void kprep(
        const float* __restrict__ fsW, const float* __restrict__ fw,
        const float* __restrict__ W, const int* __restrict__ row,
        float* __restrict__ u, float* __restrict__ v,
        unsigned short* __restrict__ wt, int* __restrict__ hist_t) {
    __shared__ int h[NBK];
    __shared__ float wi[128], wj[128];
    const int t = threadIdx.x, blk = blockIdx.x;
    if (blk < PBLK) {
        wt[blk * 256 + t] = f2bf(W[(size_t)t * 128 + blk]);
        for (int b = t; b < NBK; b += 256) h[b] = 0;
        __syncthreads();
        const int e0 = blk * EPB;
        for (int i = t; i < EPB; i += 256)
            atomicAdd(&h[row[e0 + i] / BROWS], 1);
        __syncthreads();
        for (int b = t; b < NBK; b += 256)
            hist_t[b * PBLK + blk] = h[b];
    } else {
        if (t < 128) wi[t] = fw[t]; else wj[t - 128] = fw[t];
        __syncthreads();
        const float* rowp = fsW + (size_t)t * OUT_DIM;
        float su = 0.f, sv = 0.f;
        for (int d = 0; d < 128; d += 4) {
            float4 a = *(const float4*)(rowp + d);
            su += a.x * wi[d] + a.y * wi[d + 1] + a.z * wi[d + 2] + a.w * wi[d + 3];
            sv += a.x * wj[d] + a.y * wj[d + 1] + a.z * wj[d + 2] + a.w * wj[d + 3];
        }
        u[t] = su; v[t] = sv;
    }
}

// ------- Kernel 1: MFMA GEMM, 4-phase pipelined (T3/T14: issue-early loads,
// raw s_barrier w/o vmcnt drain). Tile 64 rows x 128 cols; stage stride 72. -------
__global__ __launch_bounds__(256) void gemm_mfma(
        const float* __restrict__ x, const unsigned short* __restrict__ wt,
        const float* __restrict__ u, const float* __restrict__ v,
        unsigned short* __restrict__ psb, float* __restrict__ si, float* __restrict__ sj) {
    __shared__ unsigned short xa[64 * 136];   // staging uses [64][72]; C-tile reuse needs [64][128]

    const int t = threadIdx.x;
    const int wave = t >> 6, lane = t & 63;
    const int l15 = lane & 15, lhi = lane >> 4;
    const int row = t >> 2, quad = t & 3;
    const int brow = blockIdx.x * 64;
    const int gnode = brow + row;
    const bool valid = gnode < N_NODES;

    f32x4 acc[4][2];
#pragma unroll
    for (int mi = 0; mi < 4; ++mi)
#pragma unroll
        for (int ni = 0; ni < 2; ++ni) acc[mi][ni] = (f32x4){0.f, 0.f, 0.f, 0.f};
    float su = 0.f, sv = 0.f;

    const float* xp = x + (size_t)gnode * IN_DIM + quad * 16;
    float4 xr[4];
#pragma unroll
    for (int i = 0; i < 4; ++i) xr[i] = make_float4(0.f, 0.f, 0.f, 0.f);
    if (valid) {
#pragma unroll
        for (int i = 0; i < 4; ++i) xr[i] = ((const float4*)xp)[i];
    }

#pragma unroll
    for (int ph = 0; ph < 4; ++ph) {
        // ---- write-late: u/v (L1-broadcast) + si/sj FMAs + cvt + ds_write ----
        {
            const float* up = u + ph * 64 + quad * 16;
            const float* vp = v + ph * 64 + quad * 16;
            float4 uu0 = ((const float4*)up)[0], uu1 = ((const float4*)up)[1];
            float4 uu2 = ((const float4*)up)[2], uu3 = ((const float4*)up)[3];
            float4 vv0 = ((const float4*)vp)[0], vv1 = ((const float4*)vp)[1];
            float4 vv2 = ((const float4*)vp)[2], vv3 = ((const float4*)vp)[3];
            su = fmaf(xr[0].x, uu0.x, su); su = fmaf(xr[0].y, uu0.y, su);
            su = fmaf(xr[0].z, uu0.z, su); su = fmaf(xr[0].w, uu0.w, su);
            su = fmaf(xr[1].x, uu1.x, su); su = fmaf(xr[1].y, uu1.y, su);
            su = fmaf(xr[1].z, uu1.z, su); su = fmaf(xr[1].w, uu1.w, su);
            su = fmaf(xr[2].x, uu2.x, su); su = fmaf(xr[2].y, uu2.y, su);
            su = fmaf(xr[2].z, uu2.z, su); su = fmaf(xr[2].w, uu2.w, su);
            su = fmaf(xr[3].x, uu3.x, su); su = fmaf(xr[3].y, uu3.y, su);
            su = fmaf(xr[3].z, uu3.z, su); su = fmaf(xr[3].w, uu3.w, su);
            sv = fmaf(xr[0].x, vv0.x, sv); sv = fmaf(xr[0].y, vv0.y, sv);
            sv = fmaf(xr[0].z, vv0.z, sv); sv = fmaf(xr[0].w, vv0.w, sv);
            sv = fmaf(xr[1].x, vv1.x, sv); sv = fmaf(xr[1].y, vv1.y, sv);
            sv = fmaf(xr[1].z, vv1.z, sv); sv = fmaf(xr[1].w, vv1.w, sv);
            sv = fmaf(xr[2].x, vv2.x, sv); sv = fmaf(xr[2].y, vv2.y, sv);
            sv = fmaf(xr[2].z, vv2.z, sv); sv = fmaf(xr[2].w, vv2.w, sv);
            sv = fmaf(xr[3].x, vv3.x, sv); sv = fmaf(xr[3].y, vv3.y, sv);
            sv = fmaf(xr[3].z, vv3.z, sv); sv = fmaf(xr[3].w, vv3.w, sv);
            union { unsigned short h[16]; uint4 q[2]; } pk;
#pragma unroll
            for (int i = 0; i < 4; ++i) {
                pk.h[i * 4 + 0] = f2bf(xr[i].x); pk.h[i * 4 + 1] = f2bf(xr[i].y);
                pk.h[i * 4 + 2] = f2bf(xr[i].z); pk.h[i * 4 + 3] = f2bf(xr[i].w);
            }
            *(uint4*)&xa[row * 72 + quad * 16]     = pk.q[0];
            *(uint4*)&xa[row * 72 + quad * 16 + 8] = pk.q[1];
        }
        // ---- issue-early: next phase's x loads (stay in flight across barriers) ----
        if (ph < 3) {
            const float* xpn = xp + (ph + 1) * 64;
            if (valid) {
#pragma unroll
                for (int i = 0; i < 4; ++i) xr[i] = ((const float4*)xpn)[i];
            }
        }
        asm volatile("s_waitcnt lgkmcnt(0)" ::: "memory");   // ds_write visible
        __builtin_amdgcn_s_barrier();                        // no vmcnt drain
        // ---- MFMA: 2 K-steps; B-frags direct from L2-hot wt ----
        {
            const unsigned short* wb0 = wt + (size_t)(wave * 32 + l15) * IN_DIM + ph * 64 + lhi * 8;
            s16x8 bfr[2][2];
#pragma unroll
            for (int ks = 0; ks < 2; ++ks) {
                bfr[ks][0] = *(const s16x8*)(wb0 + ks * 32);
                bfr[ks][1] = *(const s16x8*)(wb0 + (size_t)16 * IN_DIM + ks * 32);
            }
#pragma unroll
            for (int ks = 0; ks < 2; ++ks) {
                const int k0 = ks * 32 + lhi * 8;
                s16x8 afr[4];
#pragma unroll
                for (int mi = 0; mi < 4; ++mi)
                    afr[mi] = *(const s16x8*)&xa[(mi * 16 + l15) * 72 + k0];
#pragma unroll
                for (int mi = 0; mi < 4; ++mi)
#pragma unroll
                    for (int ni = 0; ni < 2; ++ni)
                        acc[mi][ni] = __builtin_amdgcn_mfma_f32_16x16x32_bf16(
                            afr[mi], bfr[ks][ni], acc[mi][ni], 0, 0, 0);
            }
        }
        __builtin_amdgcn_s_barrier();    // all reads done before next write
    }

    su += __shfl_xor(su, 1); su += __shfl_xor(su, 2);
    sv += __shfl_xor(sv, 1); sv += __shfl_xor(sv, 2);
    if (quad == 0 && valid) { si[gnode] = su; sj[gnode] = sv; }

    // ---- C-write: fragments -> LDS ([64][128] bf16) -> coalesced global ----
    unsigned short* cl = xa;
#pragma unroll
    for (int mi = 0; mi < 4; ++mi)
#pragma unroll
        for (int ni = 0; ni < 2; ++ni) {
            const int colb = wave * 32 + ni * 16 + l15;
#pragma unroll
            for (int j = 0; j < 4; ++j)
                cl[(mi * 16 + lhi * 4 + j) * 128 + colb] = f2bf(acc[mi][ni][j]);
        }
    __syncthreads();
    {
        const int rl = t >> 2;
        const int cb = (t & 3) * 32;
        if (brow + rl < N_NODES) {
            const uint4* src = (const uint4*)&cl[rl * 128 + cb];
            uint4* dst = (uint4*)&psb[(size_t)(brow + rl) * OUT_DIM + cb];
            dst[0] = src[0]; dst[1] = src[1]; dst[2] = src[2]; dst[3] = src[3];
        }
    }
}

// ------- Kernel 3: bucket sums (int4) + exclusive scan (single block) -------
__global__ __launch_bounds__(1024) void kbscan(const int* __restrict__ hist_t,
                                               int* __restrict__ bpre) {
    __shared__ int s[1024];
    const int t = threadIdx.x;
    int v = 0;
    if (t < NBK) {
        const int4* hp = (const int4*)(hist_t + t * PBLK);
#pragma unroll 4
        for (int k = 0; k < PBLK / 4; ++k) {
            int4 a = hp[k];
            v += a.x + a.y + a.z + a.w;
        }
    }
    s[t] = v;
    __syncthreads();
    for (int off = 1; off < 1024; off <<= 1) {
        int nv = (t >= off) ? s[t - off] : 0;
        __syncthreads();
        s[t] += nv;
        __syncthreads();
    }
    if (t < NBK) bpre[t] = s[t] - v;
    if (t == 1023) bpre[NBK] = s[1023];
}

// ------- Kernel 4: per-(bucket,block) offsets -------
__global__ __launch_bounds__(128) void koff(const int* __restrict__ hist_t,
                                            const int* __restrict__ bpre,
                                            int* __restrict__ off) {
    const int b = blockIdx.x, t = threadIdx.x;
    const int lane = t & 63, w = t >> 6;
    int v = hist_t[b * PBLK + t];
    int s = v;
#pragma unroll
    for (int o = 1; o < 64; o <<= 1) { int tt = __shfl_up(s, o); if (lane >= o) s += tt; }
    __shared__ int ws2[2];
    if (lane == 63) ws2[w] = s;
    __syncthreads();
    int base = (w == 1) ? ws2[0] : 0;
    off[b * PBLK + t] = bpre[b] + base + (s - v);
}

// ------- Kernel 5: partition edges into bucket-contiguous runs (packed 4B) -------
__global__ __launch_bounds__(256) void kpart1(const int* __restrict__ row,
                                              const int* __restrict__ col,
                                              const int* __restrict__ off,
                                              unsigned int* __restrict__ part) {
    __shared__ int cur[NBK];
    const int t = threadIdx.x, blk = blockIdx.x;
    for (int b = t; b < NBK; b += 256) cur[b] = off[b * PBLK + blk];
    __syncthreads();
    const int e0 = blk * EPB;
    for (int i = t; i < EPB; i += 256) {
        int r = row[e0 + i], c = col[e0 + i];
        int b = r / BROWS;
        int rl = r - b * BROWS;
        int pos = atomicAdd(&cur[b], 1);
        part[pos] = ((unsigned)rl << 17) | (unsigned)c;
    }
}

// ------- Kernel 6: per-bucket row-histogram + local scan -> offs/deg, CSR + value -------
__global__ __launch_bounds__(256) void kpart2(const unsigned int* __restrict__ part,
                                              const int* __restrict__ bpre,
                                              const float* __restrict__ si,
                                              const float* __restrict__ sj,
                                              const float* __restrict__ dia,
                                              const float* __restrict__ fb,
                                              int2* __restrict__ epack,
                                              int* __restrict__ offs,
                                              int* __restrict__ deg) {
    __shared__ int cnt[BROWS];
    __shared__ int cur[BROWS];
    __shared__ float sil[BROWS], dial[BROWS];
    __shared__ int wtot[4];
    const int b = blockIdx.x, t = threadIdx.x;
    const int rbase = b * BROWS;
    if (t < BROWS) {
        cnt[t] = 0;
        sil[t] = si[rbase + t];
        dial[t] = dia[rbase + t];
    }
    __syncthreads();
    const int bstart = bpre[b], bend = bpre[b + 1];
    for (int e = bstart + t; e < bend; e += 256)
        atomicAdd(&cnt[part[e] >> 17], 1);
    __syncthreads();
    {
        int vv = (t < BROWS) ? cnt[t] : 0;
        int lane = t & 63, w = t >> 6;
        int s = vv;
#pragma unroll
        for (int o = 1; o < 64; o <<= 1) { int tt = __shfl_up(s, o); if (lane >= o) s += tt; }
        if (lane == 63) wtot[w] = s;
        __syncthreads();
        int base = 0;
        for (int k = 0; k < w; ++k) base += wtot[k];
        int excl = base + s - vv;
        if (t < BROWS) {
            cur[t] = bstart + excl;
            offs[rbase + t] = bstart + excl;
            deg[rbase + t] = vv;
        }
    }
    __syncthreads();
    const float fbv = fb[0];
    for (int e = bstart + t; e < bend; e += 256) {
        unsigned pk = part[e];
        int rl = (int)(pk >> 17);
        int c = (int)(pk & 0x1FFFFu);
        float tval = sil[rl] + sj[c] + fbv;
        float sg = 1.f / (1.f + expf(-tval));
        float l2 = log2f(dial[rl] * dia[c]);
        float val = exp2f(-sg * l2);
        int pos = atomicAdd(&cur[rl], 1);
        epack[pos] = make_int2(c, __float_as_int(val));
    }
}

// ------- Kernel 7: per-node gather-accumulate + ReLU, 8-edge deep MLP -------
__global__ __launch_bounds__(256) void kgather(
        const int* __restrict__ offs, const int* __restrict__ deg,
        const int2* __restrict__ epack,
        const unsigned short* __restrict__ psb, float* __restrict__ out) {
    int lane = threadIdx.x & 31;
    int node = blockIdx.x * 8 + (threadIdx.x >> 5);
    if (node >= N_NODES) return;
    int start = offs[node], d = deg[node];
    const int2* ep = epack + start;
    float a0 = 0.f, a1 = 0.f, a2 = 0.f, a3 = 0.f;
    int k = 0;
    for (; k + 8 <= d; k += 8) {
        int2 e0 = ep[k],     e1 = ep[k + 1], e2 = ep[k + 2], e3 = ep[k + 3];
        int2 e4 = ep[k + 4], e5 = ep[k + 5], e6 = ep[k + 6], e7 = ep[k + 7];
        ushort4 p0 = *(const ushort4*)&psb[(size_t)e0.x * OUT_DIM + lane * 4];
        ushort4 p1 = *(const ushort4*)&psb[(size_t)e1.x * OUT_DIM + lane * 4];
        ushort4 p2 = *(const ushort4*)&psb[(size_t)e2.x * OUT_DIM + lane * 4];
        ushort4 p3 = *(const ushort4*)&psb[(size_t)e3.x * OUT_DIM + lane * 4];
        ushort4 p4 = *(const ushort4*)&psb[(size_t)e4.x * OUT_DIM + lane * 4];
        ushort4 p5 = *(const ushort4*)&psb[(size_t)e5.x * OUT_DIM + lane * 4];
        ushort4 p6 = *(const ushort4*)&psb[(size_t)e6.x * OUT_DIM + lane * 4];
        ushort4 p7 = *(const ushort4*)&psb[(size_t)e7.x * OUT_DIM + lane * 4];
        float v0 = __int_as_float(e0.y), v1 = __int_as_float(e1.y);
        float v2 = __int_as_float(e2.y), v3 = __int_as_float(e3.y);
        float v4 = __int_as_float(e4.y), v5 = __int_as_float(e5.y);
        float v6 = __int_as_float(e6.y), v7 = __int_as_float(e7.y);
        a0 = fmaf(v0, bf2f(p0.x), a0); a1 = fmaf(v0, bf2f(p0.y), a1);
        a2 = fmaf(v0, bf2f(p0.z), a2); a3 = fmaf(v0, bf2f(p0.w), a3);
        a0 = fmaf(v1, bf2f(p1.x), a0); a1 = fmaf(v1, bf2f(p1.y), a1);
        a2 = fmaf(v1, bf2f(p1.z), a2); a3 = fmaf(v1, bf2f(p1.w), a3);
        a0 = fmaf(v2, bf2f(p2.x), a0); a1 = fmaf(v2, bf2f(p2.y), a1);
        a2 = fmaf(v2, bf2f(p2.z), a2); a3 = fmaf(v2, bf2f(p2.w), a3);
        a0 = fmaf(v3, bf2f(p3.x), a0); a1 = fmaf(v3, bf2f(p3.y), a1);
        a2 = fmaf(v3, bf2f(p3.z), a2); a3 = fmaf(v3, bf2f(p3.w), a3);
        a0 = fmaf(v4, bf2f(p4.x), a0); a1 = fmaf(v4, bf2f(p4.y), a1);
        a2 = fmaf(v4, bf2f(p4.z), a2); a3 = fmaf(v4, bf2f(p4.w), a3);
        a0 = fmaf(v5, bf2f(p5.x), a0); a1 = fmaf(v5, bf2f(p5.y), a1);
        a2 = fmaf(v5, bf2f(p5.z), a2); a3 = fmaf(v5, bf2f(p5.w), a3);
        a0 = fmaf(v6, bf2f(p6.x), a0); a1 = fmaf(v6, bf2f(p6.y), a1);
        a2 = fmaf(v6, bf2f(p6.z), a2); a3 = fmaf(v6, bf2f(p6.w), a3);
        a0 = fmaf(v7, bf2f(p7.x), a0); a1 = fmaf(v7, bf2f(p7.y), a1);
        a2 = fmaf(v7, bf2f(p7.z), a2); a3 = fmaf(v7, bf2f(p7.w), a3);
    }
    for (; k < d; ++k) {
        int2 e0 = ep[k];
        float v0 = __int_as_float(e0.y);
        ushort4 p0 = *(const ushort4*)&psb[(size_t)e0.x * OUT_DIM + lane * 4];
        a0 = fmaf(v0, bf2f(p0.x), a0);
        a1 = fmaf(v0, bf2f(p0.y), a1);
        a2 = fmaf(v0, bf2f(p0.z), a2);
        a3 = fmaf(v0, bf2f(p0.w), a3);
    }
    float4 o;
    o.x = fmaxf(a0, 0.f); o.y = fmaxf(a1, 0.f);
    o.z = fmaxf(a2, 0.f); o.w = fmaxf(a3, 0.f);
    *(float4*)&out[(size_t)node * OUT_DIM + lane * 4] = o;
}

extern "C" void kernel_launch(void* const* d_in, const int* in_sizes, int n_in,
                              void* d_out, int out_size, void* d_ws, size_t ws_size,
                              hipStream_t stream) {
    const float* x   = (const float*)d_in[0];
    const float* W   = (const float*)d_in[1];
    const float* fsW = (const float*)d_in[2];
    const float* fw  = (const float*)d_in[3];
    const float* fb  = (const float*)d_in[4];
    const float* dia = (const float*)d_in[5];
    const int*   row = (const int*)d_in[6];
    const int*   col = (const int*)d_in[7];
    float* out = (float*)d_out;

    char* p = (char*)d_ws;
    auto alloc = [&](size_t bytes) -> char* {
        char* r = p; p += (bytes + 255) & ~(size_t)255; return r;
    };
    float* u      = (float*)alloc(256 * 4);
    float* v      = (float*)alloc(256 * 4);
    unsigned short* wtb = (unsigned short*)alloc((size_t)128 * 256 * 2);
    float* si     = (float*)alloc((size_t)N_NODES * 4);
    float* sj     = (float*)alloc((size_t)N_NODES * 4);
    int*   deg    = (int*)alloc((size_t)N_NODES * 4);
    int*   offs   = (int*)alloc((size_t)N_NODES * 4);
    unsigned short* psb = (unsigned short*)alloc((size_t)N_NODES * OUT_DIM * 2);
    int*   hist_t = (int*)alloc((size_t)NBK * PBLK * 4);
    int*   bpre   = (int*)alloc((size_t)(NBK + 1) * 4);
    int*   off    = (int*)alloc((size_t)NBK * PBLK * 4);
    unsigned int* part = (unsigned int*)alloc((size_t)N_EDGES * 4);
    int2*  epack  = (int2*)alloc((size_t)N_EDGES * 8);

    kprep<<<PBLK + 1, 256, 0, stream>>>(fsW, fw, W, row, u, v, wtb, hist_t);
    gemm_mfma<<<(N_NODES + 63) / 64, 256, 0, stream>>>(x, wtb, u, v, psb, si, sj);
    kbscan<<<1, 1024, 0, stream>>>(hist_t, bpre);
    koff<<<NBK, PBLK, 0, stream>>>(hist_t, bpre, off);
    kpart1<<<PBLK, 256, 0, stream>>>(row, col, off, part);
    kpart2<<<NBK, 256, 0, stream>>>(part, bpre, si, sj, dia, fb, epack, offs, deg);
    kgather<<<N_NODES / 8, 256, 0, stream>>>(offs, deg, epack, psb, out);
}